// Round 5
// baseline (1302.502 us; speedup 1.0000x reference)
//
#include <hip/hip_runtime.h>
#include <stdint.h>

typedef unsigned short u16;
typedef unsigned int u32;
typedef __attribute__((ext_vector_type(8))) short short8;
typedef __attribute__((ext_vector_type(4))) float f32x4;

#define NB 8   // XCD buckets

__device__ __forceinline__ float b2f_bits(u32 bits){ union{u32 u; float f;} v; v.u=bits; return v.f; }
__device__ __forceinline__ float bf_lo(u32 w){ return b2f_bits(w<<16); }
__device__ __forceinline__ float bf_hi(u32 w){ return b2f_bits(w & 0xffff0000u); }
__device__ __forceinline__ u16 f2bf(float f){
  union{float f; u32 u;} v; v.f=f;
  return (u16)((v.u + 0x7fffu + ((v.u>>16)&1u))>>16);   // round-to-nearest-even
}

// ---------------- graph build ----------------

__global__ void zero_k(int* __restrict__ p, int n){
  int i = blockIdx.x*256 + threadIdx.x;
  if(i<n) p[i]=0;
}

// decide whether edge_index buffer is int64 (reference dtype) or int32 (harness-normalized)
__global__ void detect_k(const long long* __restrict__ ei, int* __restrict__ flag, int n, int E){
  __shared__ int sh[256];
  int t = threadIdx.x;
  int lim = E/2 < 2048 ? E/2 : 2048;   // safe to read as int64 under both layouts
  int bad = 0;
  for(int e=t; e<lim; e+=256){
    unsigned long long v = (unsigned long long)ei[e];
    if(v >= (unsigned long long)n) bad = 1;
  }
  sh[t]=bad; __syncthreads();
  for(int off=128; off>0; off>>=1){ if(t<off) sh[t] |= sh[t+off]; __syncthreads(); }
  if(t==0) *flag = sh[0];   // 1 => data is int32
}

__device__ __forceinline__ int edge_at(const void* eiv, int is32, long long idx){
  return is32 ? ((const int*)eiv)[idx] : (int)((const long long*)eiv)[idx];
}

__device__ __forceinline__ int clampi(int v, int lo, int hi){
  return v < lo ? lo : (v > hi ? hi : v);
}

// degree count into per-bucket histograms; bucket = blockIdx.x % NB (same mapping as scat8_k)
__global__ void deg8_k(const void* __restrict__ eiv, const int* __restrict__ flag,
                       int* __restrict__ deg8, int E, int n){
  int e = blockIdx.x*256 + threadIdx.x;
  if(e>=E) return;
  int q = blockIdx.x & (NB-1);
  int is32 = *flag;
  int r = clampi(edge_at(eiv, is32, e), 0, n-1);
  atomicAdd(&deg8[q*n + r], 1);
}

__global__ void dinv8_k(const int* __restrict__ deg8, float* __restrict__ dinv, int n){
  int i = blockIdx.x*256 + threadIdx.x;
  if(i>=n) return;
  int t = 0;
  #pragma unroll
  for(int q=0;q<NB;q++) t += deg8[q*n + i];
  dinv[i] = rsqrtf((float)(t + 1));   // +1: self loop
}

// ---- exclusive scan over m = NB*n elements, 4096 per block (16/thread) ----

__global__ __launch_bounds__(256) void scan1_k(const int* __restrict__ deg, int* __restrict__ bsum, int m){
  __shared__ int sh[256];
  int b = blockIdx.x, t = threadIdx.x;
  int base = b*4096 + t*16;
  int s = 0;
  #pragma unroll
  for(int j=0;j<16;j++){ int i = base+j; if(i<m) s += deg[i]; }
  sh[t]=s; __syncthreads();
  for(int off=128; off>0; off>>=1){ if(t<off) sh[t] += sh[t+off]; __syncthreads(); }
  if(t==0) bsum[b] = sh[0];
}

__global__ __launch_bounds__(256) void scan2_k(int* __restrict__ bsum, int nb){
  __shared__ int sh[256];
  int t = threadIdx.x;
  int v = (t<nb) ? bsum[t] : 0;
  sh[t]=v; __syncthreads();
  for(int off=1; off<256; off<<=1){
    int x = (t>=off) ? sh[t-off] : 0;
    __syncthreads();
    sh[t] += x;
    __syncthreads();
  }
  if(t<nb) bsum[t] = sh[t] - v;   // exclusive
}

__global__ __launch_bounds__(256) void scan3_k(const int* __restrict__ deg, const int* __restrict__ bscan,
                        int* __restrict__ rs, int* __restrict__ cur, int m){
  __shared__ int sh[256];
  int b = blockIdx.x, t = threadIdx.x;
  int base = b*4096 + t*16;
  int v[16]; int s = 0;
  #pragma unroll
  for(int j=0;j<16;j++){ v[j] = (base+j<m) ? deg[base+j] : 0; s += v[j]; }
  sh[t]=s; __syncthreads();
  for(int off=1; off<256; off<<=1){
    int x = (t>=off) ? sh[t-off] : 0;
    __syncthreads();
    sh[t] += x;
    __syncthreads();
  }
  int excl = sh[t] - s + bscan[b];
  #pragma unroll
  for(int j=0;j<16;j++){
    if(base+j<m){ rs[base+j]=excl; cur[base+j]=excl; excl += v[j]; }
  }
}

// scatter into per-bucket CSR regions; bucket = blockIdx.x % NB so (with round-robin
// block->XCD dispatch) all writers of a bucket's contiguous region share one XCD L2
__global__ void scat8_k(const void* __restrict__ eiv, const int* __restrict__ flag,
                        int* __restrict__ cur8, int* __restrict__ csr, int E, int n){
  int e = blockIdx.x*256 + threadIdx.x;
  if(e>=E) return;
  int q = blockIdx.x & (NB-1);
  int is32 = *flag;
  int r = clampi(edge_at(eiv, is32, e), 0, n-1);
  int c = clampi(edge_at(eiv, is32, (long long)E + e), 0, n-1);
  int pos = atomicAdd(&cur8[q*n + r], 1);
  if(pos < E) csr[pos] = c;
}

// ---------------- weights prep ----------------

// pack fp32 [256][256] W into MFMA B-fragment order: [kk(8)][ct(16)][lane(64)][j(8)] bf16
__global__ void pack_k(const float* __restrict__ W, u16* __restrict__ out){
  int idx = blockIdx.x*256 + threadIdx.x;   // 65536 total
  int j  = idx & 7;
  int l  = (idx>>3) & 63;
  int ct = (idx>>9) & 15;
  int kk = idx>>13;
  int k  = kk*32 + (l>>4)*8 + j;
  int nn = ct*16 + (l&15);
  out[idx] = f2bf(W[k*256 + nn]);
}

// ---------------- propagate (3-wide, fp32) ----------------

__global__ void prop3_k(const float* __restrict__ x, const int* __restrict__ csr,
                        const int* __restrict__ rs8, const int* __restrict__ deg8,
                        const float* __restrict__ dinv, float* __restrict__ p0, int n){
  int i = blockIdx.x*256 + threadIdx.x;
  if(i>=n) return;
  float a0=0.f, a1=0.f, a2=0.f;
  #pragma unroll 1
  for(int q=0;q<NB;q++){
    int s = rs8[q*n+i], e = s + deg8[q*n+i];
    for(int t=s; t<e; t++){
      int c = csr[t];
      float w = dinv[c];
      a0 += w*x[c*3+0]; a1 += w*x[c*3+1]; a2 += w*x[c*3+2];
    }
  }
  float di = dinv[i];
  a0 += di*x[i*3+0]; a1 += di*x[i*3+1]; a2 += di*x[i*3+2];
  p0[i*3+0]=di*a0; p0[i*3+1]=di*a1; p0[i*3+2]=di*a2;
}

// ---------------- propagate (bf16, one wave per row, HALF of features per pass) ----------------
// Splitting into two column-half passes halves the gather working set (51.2MB -> 25.6MB
// of distinct lines per pass) to raise per-XCD L2 hit rate; total logical bytes unchanged.

__global__ __launch_bounds__(256) void prop256h_k(const u16* __restrict__ hin, u16* __restrict__ pout,
                          const int* __restrict__ csr, const int* __restrict__ rs8,
                          const int* __restrict__ deg8, const float* __restrict__ dinv,
                          int n, int half){
  int row = (blockIdx.x*256 + threadIdx.x) >> 6;
  if(row>=n) return;
  row = __builtin_amdgcn_readfirstlane(row);   // wave-uniform
  int lane = threadIdx.x & 63;
  int co = half*128 + lane*2;                  // 2 cols (4B) per lane
  const u16* hb = hin + co;
  // self contribution (norm = dinv[i]^2, h stored pre-scaled by dinv)
  u32 sv = *(const u32*)(hb + (size_t)row*256);
  float a0=bf_lo(sv), a1=bf_hi(sv);
  #pragma unroll 1
  for(int q=0;q<NB;q++){
    int s = __builtin_amdgcn_readfirstlane(rs8[q*n+row]);
    int d = __builtin_amdgcn_readfirstlane(deg8[q*n+row]);
    int end = s + d;
    int e = s;
    for(; e+4<=end; e+=4){
      int c0=csr[e], c1=csr[e+1], c2=csr[e+2], c3=csr[e+3];
      u32 v0 = *(const u32*)(hb + (size_t)c0*256);
      u32 v1 = *(const u32*)(hb + (size_t)c1*256);
      u32 v2 = *(const u32*)(hb + (size_t)c2*256);
      u32 v3 = *(const u32*)(hb + (size_t)c3*256);
      a0 += bf_lo(v0); a1 += bf_hi(v0);
      a0 += bf_lo(v1); a1 += bf_hi(v1);
      a0 += bf_lo(v2); a1 += bf_hi(v2);
      a0 += bf_lo(v3); a1 += bf_hi(v3);
    }
    for(; e<end; e++){
      int c = csr[e];
      u32 v = *(const u32*)(hb + (size_t)c*256);
      a0 += bf_lo(v); a1 += bf_hi(v);
    }
  }
  float sc = dinv[row];
  u32 o = (u32)f2bf(a0*sc) | ((u32)f2bf(a1*sc)<<16);
  *(u32*)(pout + (size_t)row*256 + co) = o;
}

// ---------------- GEMMs ----------------

// h1 = dinv * relu(p0 @ W0 + b0)  — K=3 skinny, one block per row
__global__ __launch_bounds__(256) void gemm0_k(const float* __restrict__ p0, const float* __restrict__ W0,
                        const float* __restrict__ b0, const float* __restrict__ dinv,
                        u16* __restrict__ h1, int n){
  int i = blockIdx.x;
  int j = threadIdx.x;
  float v = p0[i*3+0]*W0[j] + p0[i*3+1]*W0[256+j] + p0[i*3+2]*W0[512+j] + b0[j];
  v = fmaxf(v, 0.f) * dinv[i];
  h1[(size_t)i*256 + j] = f2bf(v);
}

// out = dinv * relu(A @ W + b), A [Mpad][256] bf16, W packed fragments.
__global__ __launch_bounds__(256) void gemm256_k(const u16* __restrict__ A, const u16* __restrict__ Bp,
                          const float* __restrict__ bias, const float* __restrict__ dinv,
                          u16* __restrict__ Out, int M){
  int wave = threadIdx.x>>6, lane = threadIdx.x&63;
  int rowbase = blockIdx.x*64 + wave*16;
  f32x4 acc[16];
  #pragma unroll
  for(int t=0;t<16;t++){ acc[t][0]=0.f; acc[t][1]=0.f; acc[t][2]=0.f; acc[t][3]=0.f; }
  // A fragment: row = lane&15, k = (lane>>4)*8 + j
  const u16* Ap = A + (size_t)(rowbase + (lane&15))*256 + ((lane>>4)*8);
  const u16* Bl = Bp + (size_t)lane*8;
  #pragma unroll
  for(int kk=0; kk<8; kk++){
    short8 af = *(const short8*)(Ap + kk*32);
    const u16* bb = Bl + (size_t)kk*8192;
    #pragma unroll
    for(int t=0;t<16;t++){
      short8 bf = *(const short8*)(bb + t*512);
      acc[t] = __builtin_amdgcn_mfma_f32_16x16x32_bf16(af, bf, acc[t], 0, 0, 0);
    }
  }
  // D: row = rowbase + (lane>>4)*4 + r, col = t*16 + (lane&15)
  int r0 = rowbase + (lane>>4)*4;
  float dv[4]; bool ok[4];
  #pragma unroll
  for(int r=0;r<4;r++){ ok[r] = (r0+r) < M; dv[r] = ok[r] ? dinv[r0+r] : 0.f; }
  #pragma unroll
  for(int t=0;t<16;t++){
    int col = t*16 + (lane&15);
    float bc = bias[col];
    #pragma unroll
    for(int r=0;r<4;r++){
      if(ok[r]){
        float v = fmaxf(acc[t][r] + bc, 0.f) * dv[r];
        Out[(size_t)(r0+r)*256 + col] = f2bf(v);
      }
    }
  }
}

// qhat = h3hat @ W3  (K=256 -> 3), thread per row
__global__ __launch_bounds__(256) void gemm3_k(const u16* __restrict__ h3, const float* __restrict__ W3,
                        float* __restrict__ qh, int n){
  __shared__ float w3s[768];
  for(int i=threadIdx.x; i<768; i+=256) w3s[i] = W3[i];
  __syncthreads();
  int i = blockIdx.x*256 + threadIdx.x;
  if(i>=n) return;
  float a0=0.f, a1=0.f, a2=0.f;
  const uint4* hp = (const uint4*)(h3 + (size_t)i*256);
  for(int kk=0; kk<32; kk++){
    uint4 v = hp[kk];
    float f[8] = {bf_lo(v.x),bf_hi(v.x),bf_lo(v.y),bf_hi(v.y),
                  bf_lo(v.z),bf_hi(v.z),bf_lo(v.w),bf_hi(v.w)};
    int k0 = kk*8;
    #pragma unroll
    for(int j=0;j<8;j++){
      a0 += f[j]*w3s[(k0+j)*3+0];
      a1 += f[j]*w3s[(k0+j)*3+1];
      a2 += f[j]*w3s[(k0+j)*3+2];
    }
  }
  qh[i*3+0]=a0; qh[i*3+1]=a1; qh[i*3+2]=a2;
}

// p3 = A_hat qhat (3-wide) ; out = p3 + b3 + x@Wr + br
__global__ void final_k(const float* __restrict__ qh, const float* __restrict__ x,
                        const int* __restrict__ csr, const int* __restrict__ rs8,
                        const int* __restrict__ deg8, const float* __restrict__ dinv,
                        const float* __restrict__ b3, const float* __restrict__ Wr,
                        const float* __restrict__ br, float* __restrict__ out, int n){
  int i = blockIdx.x*256 + threadIdx.x;
  if(i>=n) return;
  float a0=0.f, a1=0.f, a2=0.f;
  #pragma unroll 1
  for(int q=0;q<NB;q++){
    int s = rs8[q*n+i], e = s + deg8[q*n+i];
    for(int t=s; t<e; t++){
      int c = csr[t];
      a0 += qh[c*3+0]; a1 += qh[c*3+1]; a2 += qh[c*3+2];
    }
  }
  float di = dinv[i];
  a0 = di*(a0 + qh[i*3+0]);
  a1 = di*(a1 + qh[i*3+1]);
  a2 = di*(a2 + qh[i*3+2]);
  float x0=x[i*3+0], x1=x[i*3+1], x2=x[i*3+2];
  out[i*3+0] = a0 + b3[0] + x0*Wr[0] + x1*Wr[3] + x2*Wr[6] + br[0];
  out[i*3+1] = a1 + b3[1] + x0*Wr[1] + x1*Wr[4] + x2*Wr[7] + br[1];
  out[i*3+2] = a2 + b3[2] + x0*Wr[2] + x1*Wr[5] + x2*Wr[8] + br[2];
}

// ---------------- launch ----------------

extern "C" void kernel_launch(void* const* d_in, const int* in_sizes, int n_in,
                              void* d_out, int out_size, void* d_ws, size_t ws_size,
                              hipStream_t stream) {
  const float* x  = (const float*)d_in[0];
  const void*  ei = d_in[1];                  // int64 per reference; detect on device
  const float* W0 = (const float*)d_in[2];
  const float* b0 = (const float*)d_in[3];
  const float* W1 = (const float*)d_in[4];
  const float* b1 = (const float*)d_in[5];
  const float* W2 = (const float*)d_in[6];
  const float* b2 = (const float*)d_in[7];
  const float* W3 = (const float*)d_in[8];
  const float* b3 = (const float*)d_in[9];
  const float* Wr = (const float*)d_in[10];
  const float* br = (const float*)d_in[11];
  float* out = (float*)d_out;

  int n = in_sizes[0]/3;
  int E = in_sizes[1]/2;
  int m8 = NB*n;                       // bucketed histogram size
  int Mpad = ((n+63)/64)*64;
  int nb8 = (m8+4095)/4096;            // scan blocks (4096 elems each); 100k*8 -> 196 <= 256

  char* p = (char*)d_ws;
  auto alloc = [&](size_t bytes)->char*{ char* r=p; p += (bytes+255)&~(size_t)255; return r; };
  int*   deg8  = (int*)  alloc((size_t)m8*4);
  float* dinv  = (float*)alloc((size_t)n*4);
  int*   rs8   = (int*)  alloc((size_t)m8*4);
  int*   cur8  = (int*)  alloc((size_t)m8*4);
  int*   bsum  = (int*)  alloc(256*4);
  int*   flag  = (int*)  alloc(256);
  int*   csr   = (int*)  alloc((size_t)E*4);
  u16*   hA    = (u16*)  alloc((size_t)Mpad*512);
  u16*   hB    = (u16*)  alloc((size_t)Mpad*512);
  float* p0    = (float*)alloc((size_t)n*12);
  float* qh    = (float*)alloc((size_t)n*12);
  u16*   W1p   = (u16*)  alloc(65536*2);
  u16*   W2p   = (u16*)  alloc(65536*2);

  int gn  = (n+255)/256;
  int gE  = (E+255)/256;
  int gm8 = (m8+255)/256;
  int gp  = (n*64+255)/256;            // prop grid: one wave per row

  // graph build (8-bucket counting sort keyed by blockIdx%8 ~ XCD)
  zero_k  <<<gm8, 256, 0, stream>>>(deg8, m8);
  detect_k<<<1, 256, 0, stream>>>((const long long*)ei, flag, n, E);
  deg8_k  <<<gE, 256, 0, stream>>>(ei, flag, deg8, E, n);
  dinv8_k <<<gn, 256, 0, stream>>>(deg8, dinv, n);
  scan1_k <<<nb8, 256, 0, stream>>>(deg8, bsum, m8);
  scan2_k <<<1, 256, 0, stream>>>(bsum, nb8);
  scan3_k <<<nb8, 256, 0, stream>>>(deg8, bsum, rs8, cur8, m8);
  scat8_k <<<gE, 256, 0, stream>>>(ei, flag, cur8, csr, E, n);

  // weights
  pack_k  <<<256, 256, 0, stream>>>(W1, W1p);
  pack_k  <<<256, 256, 0, stream>>>(W2, W2p);

  // layer 0: p0 = A x ; h1hat = dinv*relu(p0 W0 + b0)
  prop3_k <<<gn, 256, 0, stream>>>(x, csr, rs8, deg8, dinv, p0, n);
  gemm0_k <<<n, 256, 0, stream>>>(p0, W0, b0, dinv, hA, n);

  // layer 1 (two column-half passes to shrink gather working set)
  prop256h_k<<<gp, 256, 0, stream>>>(hA, hB, csr, rs8, deg8, dinv, n, 0);
  prop256h_k<<<gp, 256, 0, stream>>>(hA, hB, csr, rs8, deg8, dinv, n, 1);
  gemm256_k<<<Mpad/64, 256, 0, stream>>>(hB, W1p, b1, dinv, hA, n);

  // layer 2
  prop256h_k<<<gp, 256, 0, stream>>>(hA, hB, csr, rs8, deg8, dinv, n, 0);
  prop256h_k<<<gp, 256, 0, stream>>>(hA, hB, csr, rs8, deg8, dinv, n, 1);
  gemm256_k<<<Mpad/64, 256, 0, stream>>>(hB, W2p, b2, dinv, hA, n);

  // layer 3 (reordered: qhat = h3hat @ W3, then 3-wide propagate) + skip
  gemm3_k <<<gn, 256, 0, stream>>>(hA, W3, qh, n);
  final_k <<<gn, 256, 0, stream>>>(qh, x, csr, rs8, deg8, dinv, b3, Wr, br, out, n);
}

// Round 6
// 907.866 us; speedup vs baseline: 1.4347x; 1.4347x over previous
//
#include <hip/hip_runtime.h>
#include <stdint.h>

typedef unsigned short u16;
typedef unsigned int u32;
typedef __attribute__((ext_vector_type(8))) short short8;
typedef __attribute__((ext_vector_type(4))) float f32x4;

#define CAP 6144        // pairs per coarse bucket region (mean ~4096, huge margin)
#define TILE 4096       // edges per binA block

__device__ __forceinline__ float b2f_bits(u32 bits){ union{u32 u; float f;} v; v.u=bits; return v.f; }
__device__ __forceinline__ float bf_lo(u32 w){ return b2f_bits(w<<16); }
__device__ __forceinline__ float bf_hi(u32 w){ return b2f_bits(w & 0xffff0000u); }
__device__ __forceinline__ u16 f2bf(float f){
  union{float f; u32 u;} v; v.f=f;
  return (u16)((v.u + 0x7fffu + ((v.u>>16)&1u))>>16);   // round-to-nearest-even
}

__global__ void zero_k(int* __restrict__ p, int n){
  int i = blockIdx.x*256 + threadIdx.x;
  if(i<n) p[i]=0;
}

// decide whether edge_index buffer is int64 (reference dtype) or int32 (harness-normalized)
__global__ void detect_k(const long long* __restrict__ ei, int* __restrict__ flag, int n, int E){
  __shared__ int sh[256];
  int t = threadIdx.x;
  int lim = E/2 < 2048 ? E/2 : 2048;
  int bad = 0;
  for(int e=t; e<lim; e+=256){
    unsigned long long v = (unsigned long long)ei[e];
    if(v >= (unsigned long long)n) bad = 1;
  }
  sh[t]=bad; __syncthreads();
  for(int off=128; off>0; off>>=1){ if(t<off) sh[t] |= sh[t+off]; __syncthreads(); }
  if(t==0) *flag = sh[0];   // 1 => data is int32
}

__device__ __forceinline__ int edge_at(const void* eiv, int is32, long long idx){
  return is32 ? ((const int*)eiv)[idx] : (int)((const long long*)eiv)[idx];
}
__device__ __forceinline__ int clampi(int v, int lo, int hi){
  return v < lo ? lo : (v > hi ? hi : v);
}

// ---------------- pass A: tile-level counting sort into coarse buckets ----------------
// bucket b = row>>7 (128 rows/bucket). Per-tile: LDS hist -> scan -> LDS scatter ->
// dense flush (one global cursor claim per (bucket,tile)). Pairs packed 4B: (r&127)<<17 | c.
__global__ __launch_bounds__(256) void binA_k(const void* __restrict__ eiv, const int* __restrict__ flag,
                        int* __restrict__ gcur, u32* __restrict__ gbuf, int E, int n, int nbuck){
  __shared__ int hist[1024];
  __shared__ int base[1024];
  __shared__ int cur[1024];
  __shared__ int wsum[256];
  __shared__ u32 stage[TILE];
  int t = threadIdx.x;
  long long e0 = (long long)blockIdx.x * TILE;
  int cnt = (int)((long long)E - e0 < TILE ? (long long)E - e0 : TILE);
  int is32 = *flag;
  for(int i=t; i<nbuck; i+=256){ hist[i]=0; cur[i]=0; }
  __syncthreads();
  // local edges
  int eb[16]; u32 ep[16]; int ec=0;
  #pragma unroll
  for(int k=0;k<16;k++){
    int i = t + k*256;
    if(i<cnt){
      long long e = e0 + i;
      int r = clampi(edge_at(eiv,is32,e),0,n-1);
      int c = clampi(edge_at(eiv,is32,(long long)E+e),0,n-1);
      eb[ec] = r>>7;
      ep[ec] = ((u32)(r&127)<<17) | (u32)c;
      atomicAdd(&hist[eb[ec]],1);
      ec++;
    }
  }
  __syncthreads();
  // exclusive scan of hist[0..nbuck) (256 threads x 4)
  int l[4]; int tot=0;
  #pragma unroll
  for(int j=0;j<4;j++){ int idx=t*4+j; l[j]=(idx<nbuck)?hist[idx]:0; tot+=l[j]; }
  wsum[t]=tot; __syncthreads();
  for(int off=1;off<256;off<<=1){
    int x = (t>=off)?wsum[t-off]:0;
    __syncthreads();
    wsum[t]+=x;
    __syncthreads();
  }
  int excl = wsum[t]-tot;
  #pragma unroll
  for(int j=0;j<4;j++){ int idx=t*4+j; if(idx<nbuck) base[idx]=excl; excl+=l[j]; }
  __syncthreads();
  // LDS scatter
  for(int k=0;k<ec;k++){
    int b = eb[k];
    int slot = base[b] + atomicAdd(&cur[b],1);
    stage[slot] = ep[k];
  }
  __syncthreads();
  // dense flush: one cursor claim per bucket, contiguous run
  for(int b=t; b<nbuck; b+=256){
    int c = hist[b];
    if(c>0){
      int g = atomicAdd(&gcur[b], c);
      if(g > CAP) g = CAP;
      if(g + c > CAP) c = CAP - g;
      int src = base[b];
      u32* dst = gbuf + (size_t)b*CAP + g;
      for(int k=0;k<c;k++) dst[k] = stage[src+k];
    }
  }
}

// ---------------- pass B1: per-bucket degree (no global atomics) ----------------
__global__ __launch_bounds__(256) void degB_k(const int* __restrict__ gcnt, const u32* __restrict__ gbuf,
                        int* __restrict__ deg, int n, int nbuck){
  __shared__ int h[128];
  int b = blockIdx.x, t = threadIdx.x;
  if(t<128) h[t]=0;
  __syncthreads();
  int c = gcnt[b]; if(c>CAP) c=CAP;
  const u32* p = gbuf + (size_t)b*CAP;
  for(int i=t;i<c;i+=256) atomicAdd(&h[p[i]>>17],1);
  __syncthreads();
  int row = b*128 + t;
  if(t<128 && row<n) deg[row]=h[t];
}

__global__ void dinv_k(const int* __restrict__ deg, float* __restrict__ dinv, int n){
  int i = blockIdx.x*256 + threadIdx.x;
  if(i<n) dinv[i] = rsqrtf((float)(deg[i] + 1));   // +1: self loop
}

// ---- exclusive scan over n elements, 4096 per block ----
__global__ __launch_bounds__(256) void scan1_k(const int* __restrict__ deg, int* __restrict__ bsum, int m){
  __shared__ int sh[256];
  int b = blockIdx.x, t = threadIdx.x;
  int base = b*4096 + t*16;
  int s = 0;
  #pragma unroll
  for(int j=0;j<16;j++){ int i = base+j; if(i<m) s += deg[i]; }
  sh[t]=s; __syncthreads();
  for(int off=128; off>0; off>>=1){ if(t<off) sh[t] += sh[t+off]; __syncthreads(); }
  if(t==0) bsum[b] = sh[0];
}

__global__ __launch_bounds__(256) void scan2_k(int* __restrict__ bsum, int nb){
  __shared__ int sh[256];
  int t = threadIdx.x;
  int v = (t<nb) ? bsum[t] : 0;
  sh[t]=v; __syncthreads();
  for(int off=1; off<256; off<<=1){
    int x = (t>=off) ? sh[t-off] : 0;
    __syncthreads();
    sh[t] += x;
    __syncthreads();
  }
  if(t<nb) bsum[t] = sh[t] - v;   // exclusive
}

__global__ __launch_bounds__(256) void scan3_k(const int* __restrict__ deg, const int* __restrict__ bscan,
                        int* __restrict__ rs, int m){
  __shared__ int sh[256];
  int b = blockIdx.x, t = threadIdx.x;
  int base = b*4096 + t*16;
  int v[16]; int s = 0;
  #pragma unroll
  for(int j=0;j<16;j++){ v[j] = (base+j<m) ? deg[base+j] : 0; s += v[j]; }
  sh[t]=s; __syncthreads();
  for(int off=1; off<256; off<<=1){
    int x = (t>=off) ? sh[t-off] : 0;
    __syncthreads();
    sh[t] += x;
    __syncthreads();
  }
  int excl = sh[t] - s + bscan[b];
  #pragma unroll
  for(int j=0;j<16;j++){
    if(base+j<m){ rs[base+j]=excl; excl += v[j]; }
  }
}

// ---------------- pass B2: per-bucket CSR materialization (dense contiguous writes) ----------------
__global__ __launch_bounds__(256) void csrB_k(const int* __restrict__ gcnt, const u32* __restrict__ gbuf,
                        const int* __restrict__ rs, const int* __restrict__ deg,
                        int* __restrict__ csr, int n, int nbuck){
  __shared__ int sc[128];      // inclusive scan of local degs
  __shared__ int lst[128];     // exclusive starts
  __shared__ int lcur[128];
  __shared__ int colstage[CAP];
  int b = blockIdx.x, t = threadIdx.x;
  int row0 = b*128;
  int dv = 0;
  if(t<128){ int row=row0+t; dv=(row<n)?deg[row]:0; sc[t]=dv; lcur[t]=0; }
  __syncthreads();
  for(int off=1;off<128;off<<=1){
    int x = (t>=off && t<128) ? sc[t-off] : 0;
    __syncthreads();
    if(t<128) sc[t]+=x;
    __syncthreads();
  }
  if(t<128) lst[t]=sc[t]-dv;
  __syncthreads();
  int c = gcnt[b]; if(c>CAP) c=CAP;
  const u32* p = gbuf + (size_t)b*CAP;
  for(int i=t;i<c;i+=256){
    u32 pr = p[i];
    int rl = pr>>17;
    int slot = lst[rl] + atomicAdd(&lcur[rl],1);
    if(slot < CAP) colstage[slot] = (int)(pr & 0x1FFFFu);
  }
  __syncthreads();
  int tot = sc[127]; if(tot>c) tot=c;
  int gbase = rs[row0];
  for(int i=t;i<tot;i+=256) csr[gbase+i] = colstage[i];
}

// ---------------- weights prep ----------------
// pack fp32 [256][256] W into MFMA B-fragment order: [kk(8)][ct(16)][lane(64)][j(8)] bf16
__global__ void pack_k(const float* __restrict__ W, u16* __restrict__ out){
  int idx = blockIdx.x*256 + threadIdx.x;   // 65536 total
  int j  = idx & 7;
  int l  = (idx>>3) & 63;
  int ct = (idx>>9) & 15;
  int kk = idx>>13;
  int k  = kk*32 + (l>>4)*8 + j;
  int nn = ct*16 + (l&15);
  out[idx] = f2bf(W[k*256 + nn]);
}

// ---------------- propagate (3-wide, fp32) ----------------
__global__ void prop3_k(const float* __restrict__ x, const int* __restrict__ csr,
                        const int* __restrict__ rs, const int* __restrict__ deg,
                        const float* __restrict__ dinv, float* __restrict__ p0, int n){
  int i = blockIdx.x*256 + threadIdx.x;
  if(i>=n) return;
  float a0=0.f, a1=0.f, a2=0.f;
  int s = rs[i], e = s + deg[i];
  for(int t=s; t<e; t++){
    int c = csr[t];
    float w = dinv[c];
    a0 += w*x[c*3+0]; a1 += w*x[c*3+1]; a2 += w*x[c*3+2];
  }
  float di = dinv[i];
  a0 += di*x[i*3+0]; a1 += di*x[i*3+1]; a2 += di*x[i*3+2];
  p0[i*3+0]=di*a0; p0[i*3+1]=di*a1; p0[i*3+2]=di*a2;
}

// ---------------- propagate (256-wide bf16, one wave/row, 16 gathers in flight) ----------------
__global__ __launch_bounds__(256) void prop256_k(const u16* __restrict__ hin, u16* __restrict__ pout,
                          const int* __restrict__ csr, const int* __restrict__ rs,
                          const int* __restrict__ deg, const float* __restrict__ dinv, int n){
  int row = (blockIdx.x*256 + threadIdx.x) >> 6;
  if(row>=n) return;
  row = __builtin_amdgcn_readfirstlane(row);
  int lane = threadIdx.x & 63;
  int co = lane*4;
  const u16* hb = hin + co;
  uint2 sv = *(const uint2*)(hb + (size_t)row*256);
  float a0=bf_lo(sv.x), a1=bf_hi(sv.x), a2=bf_lo(sv.y), a3=bf_hi(sv.y);
  int s = __builtin_amdgcn_readfirstlane(rs[row]);
  int d = __builtin_amdgcn_readfirstlane(deg[row]);
  for(int base=0; base<d; base+=16){
    int cc[16]; u32 mk[16];
    #pragma unroll
    for(int j=0;j<16;j++){
      int ok = (base+j) < d;                 // wave-uniform
      cc[j] = csr[ok ? (s+base+j) : s];
      mk[j] = ok ? 0xffffffffu : 0u;
    }
    uint2 v[16];
    #pragma unroll
    for(int j=0;j<16;j++) v[j] = *(const uint2*)(hb + (size_t)cc[j]*256);
    #pragma unroll
    for(int j=0;j<16;j++){
      u32 xw = v[j].x & mk[j], yw = v[j].y & mk[j];
      a0 += bf_lo(xw); a1 += bf_hi(xw); a2 += bf_lo(yw); a3 += bf_hi(yw);
    }
  }
  float sc = dinv[row];
  uint2 o;
  o.x = (u32)f2bf(a0*sc) | ((u32)f2bf(a1*sc)<<16);
  o.y = (u32)f2bf(a2*sc) | ((u32)f2bf(a3*sc)<<16);
  *(uint2*)(pout + (size_t)row*256 + co) = o;
}

// ---------------- GEMMs ----------------
__global__ __launch_bounds__(256) void gemm0_k(const float* __restrict__ p0, const float* __restrict__ W0,
                        const float* __restrict__ b0, const float* __restrict__ dinv,
                        u16* __restrict__ h1, int n){
  int i = blockIdx.x;
  int j = threadIdx.x;
  float v = p0[i*3+0]*W0[j] + p0[i*3+1]*W0[256+j] + p0[i*3+2]*W0[512+j] + b0[j];
  v = fmaxf(v, 0.f) * dinv[i];
  h1[(size_t)i*256 + j] = f2bf(v);
}

__global__ __launch_bounds__(256) void gemm256_k(const u16* __restrict__ A, const u16* __restrict__ Bp,
                          const float* __restrict__ bias, const float* __restrict__ dinv,
                          u16* __restrict__ Out, int M){
  int wave = threadIdx.x>>6, lane = threadIdx.x&63;
  int rowbase = blockIdx.x*64 + wave*16;
  f32x4 acc[16];
  #pragma unroll
  for(int t=0;t<16;t++){ acc[t][0]=0.f; acc[t][1]=0.f; acc[t][2]=0.f; acc[t][3]=0.f; }
  const u16* Ap = A + (size_t)(rowbase + (lane&15))*256 + ((lane>>4)*8);
  const u16* Bl = Bp + (size_t)lane*8;
  #pragma unroll
  for(int kk=0; kk<8; kk++){
    short8 af = *(const short8*)(Ap + kk*32);
    const u16* bb = Bl + (size_t)kk*8192;
    #pragma unroll
    for(int t=0;t<16;t++){
      short8 bf = *(const short8*)(bb + t*512);
      acc[t] = __builtin_amdgcn_mfma_f32_16x16x32_bf16(af, bf, acc[t], 0, 0, 0);
    }
  }
  int r0 = rowbase + (lane>>4)*4;
  float dv[4]; bool ok[4];
  #pragma unroll
  for(int r=0;r<4;r++){ ok[r] = (r0+r) < M; dv[r] = ok[r] ? dinv[r0+r] : 0.f; }
  #pragma unroll
  for(int t=0;t<16;t++){
    int col = t*16 + (lane&15);
    float bc = bias[col];
    #pragma unroll
    for(int r=0;r<4;r++){
      if(ok[r]){
        float v = fmaxf(acc[t][r] + bc, 0.f) * dv[r];
        Out[(size_t)(r0+r)*256 + col] = f2bf(v);
      }
    }
  }
}

__global__ __launch_bounds__(256) void gemm3_k(const u16* __restrict__ h3, const float* __restrict__ W3,
                        float* __restrict__ qh, int n){
  __shared__ float w3s[768];
  for(int i=threadIdx.x; i<768; i+=256) w3s[i] = W3[i];
  __syncthreads();
  int i = blockIdx.x*256 + threadIdx.x;
  if(i>=n) return;
  float a0=0.f, a1=0.f, a2=0.f;
  const uint4* hp = (const uint4*)(h3 + (size_t)i*256);
  for(int kk=0; kk<32; kk++){
    uint4 v = hp[kk];
    float f[8] = {bf_lo(v.x),bf_hi(v.x),bf_lo(v.y),bf_hi(v.y),
                  bf_lo(v.z),bf_hi(v.z),bf_lo(v.w),bf_hi(v.w)};
    int k0 = kk*8;
    #pragma unroll
    for(int j=0;j<8;j++){
      a0 += f[j]*w3s[(k0+j)*3+0];
      a1 += f[j]*w3s[(k0+j)*3+1];
      a2 += f[j]*w3s[(k0+j)*3+2];
    }
  }
  qh[i*3+0]=a0; qh[i*3+1]=a1; qh[i*3+2]=a2;
}

__global__ void final_k(const float* __restrict__ qh, const float* __restrict__ x,
                        const int* __restrict__ csr, const int* __restrict__ rs,
                        const int* __restrict__ deg, const float* __restrict__ dinv,
                        const float* __restrict__ b3, const float* __restrict__ Wr,
                        const float* __restrict__ br, float* __restrict__ out, int n){
  int i = blockIdx.x*256 + threadIdx.x;
  if(i>=n) return;
  float a0=0.f, a1=0.f, a2=0.f;
  int s = rs[i], e = s + deg[i];
  for(int t=s; t<e; t++){
    int c = csr[t];
    a0 += qh[c*3+0]; a1 += qh[c*3+1]; a2 += qh[c*3+2];
  }
  float di = dinv[i];
  a0 = di*(a0 + qh[i*3+0]);
  a1 = di*(a1 + qh[i*3+1]);
  a2 = di*(a2 + qh[i*3+2]);
  float x0=x[i*3+0], x1=x[i*3+1], x2=x[i*3+2];
  out[i*3+0] = a0 + b3[0] + x0*Wr[0] + x1*Wr[3] + x2*Wr[6] + br[0];
  out[i*3+1] = a1 + b3[1] + x0*Wr[1] + x1*Wr[4] + x2*Wr[7] + br[1];
  out[i*3+2] = a2 + b3[2] + x0*Wr[2] + x1*Wr[5] + x2*Wr[8] + br[2];
}

// ---------------- launch ----------------
extern "C" void kernel_launch(void* const* d_in, const int* in_sizes, int n_in,
                              void* d_out, int out_size, void* d_ws, size_t ws_size,
                              hipStream_t stream) {
  const float* x  = (const float*)d_in[0];
  const void*  ei = d_in[1];
  const float* W0 = (const float*)d_in[2];
  const float* b0 = (const float*)d_in[3];
  const float* W1 = (const float*)d_in[4];
  const float* b1 = (const float*)d_in[5];
  const float* W2 = (const float*)d_in[6];
  const float* b2 = (const float*)d_in[7];
  const float* W3 = (const float*)d_in[8];
  const float* b3 = (const float*)d_in[9];
  const float* Wr = (const float*)d_in[10];
  const float* br = (const float*)d_in[11];
  float* out = (float*)d_out;

  int n = in_sizes[0]/3;
  int E = in_sizes[1]/2;
  int nbuck = (n+127)>>7;              // 128 rows per bucket; <=1024 for n<=131072
  int Mpad = ((n+63)/64)*64;
  int nbscan = (n+4095)/4096;

  char* p = (char*)d_ws;
  auto alloc = [&](size_t bytes)->char*{ char* r=p; p += (bytes+255)&~(size_t)255; return r; };
  int*   gcur  = (int*)  alloc((size_t)nbuck*4);
  int*   deg   = (int*)  alloc((size_t)n*4);
  float* dinv  = (float*)alloc((size_t)n*4);
  int*   rs    = (int*)  alloc((size_t)n*4);
  int*   bsum  = (int*)  alloc(256*4);
  int*   flag  = (int*)  alloc(256);
  int*   csr   = (int*)  alloc((size_t)E*4);
  u16*   hA    = (u16*)  alloc((size_t)Mpad*512);
  u16*   hB    = (u16*)  alloc((size_t)Mpad*512);
  float* p0    = (float*)alloc((size_t)n*12);
  float* qh    = (float*)alloc((size_t)n*12);
  u16*   W1p   = (u16*)  alloc(65536*2);
  u16*   W2p   = (u16*)  alloc(65536*2);
  // gbuf (nbuck*CAP*4 ~ 19.2MB) aliases hA (51.2MB): dead before gemm0 writes hA
  u32*   gbuf  = (u32*)hA;

  int gn  = (n+255)/256;
  int gA  = (E+TILE-1)/TILE;
  int gp  = (n*64+255)/256;            // prop grid: one wave per row

  // graph build: 2-pass LDS-staged counting sort
  zero_k  <<<(nbuck+255)/256, 256, 0, stream>>>(gcur, nbuck);
  detect_k<<<1, 256, 0, stream>>>((const long long*)ei, flag, n, E);
  binA_k  <<<gA, 256, 0, stream>>>(ei, flag, gcur, gbuf, E, n, nbuck);
  degB_k  <<<nbuck, 256, 0, stream>>>(gcur, gbuf, deg, n, nbuck);
  dinv_k  <<<gn, 256, 0, stream>>>(deg, dinv, n);
  scan1_k <<<nbscan, 256, 0, stream>>>(deg, bsum, n);
  scan2_k <<<1, 256, 0, stream>>>(bsum, nbscan);
  scan3_k <<<nbscan, 256, 0, stream>>>(deg, bsum, rs, n);
  csrB_k  <<<nbuck, 256, 0, stream>>>(gcur, gbuf, rs, deg, csr, n, nbuck);

  // weights
  pack_k  <<<256, 256, 0, stream>>>(W1, W1p);
  pack_k  <<<256, 256, 0, stream>>>(W2, W2p);

  // layer 0
  prop3_k <<<gn, 256, 0, stream>>>(x, csr, rs, deg, dinv, p0, n);
  gemm0_k <<<n, 256, 0, stream>>>(p0, W0, b0, dinv, hA, n);

  // layer 1
  prop256_k<<<gp, 256, 0, stream>>>(hA, hB, csr, rs, deg, dinv, n);
  gemm256_k<<<Mpad/64, 256, 0, stream>>>(hB, W1p, b1, dinv, hA, n);

  // layer 2
  prop256_k<<<gp, 256, 0, stream>>>(hA, hB, csr, rs, deg, dinv, n);
  gemm256_k<<<Mpad/64, 256, 0, stream>>>(hB, W2p, b2, dinv, hA, n);

  // layer 3 + skip
  gemm3_k <<<gn, 256, 0, stream>>>(hA, W3, qh, n);
  final_k <<<gn, 256, 0, stream>>>(qh, x, csr, rs, deg, dinv, b3, Wr, br, out, n);
}

// Round 7
// 906.577 us; speedup vs baseline: 1.4367x; 1.0014x over previous
//
#include <hip/hip_runtime.h>
#include <stdint.h>

typedef unsigned short u16;
typedef unsigned int u32;
typedef __attribute__((ext_vector_type(8))) short short8;
typedef __attribute__((ext_vector_type(4))) float f32x4;

#define CAP 6144        // pairs per coarse bucket region (mean ~4096, +32 sigma margin)
#define TILE 4096       // edges per binA block

__device__ __forceinline__ float b2f_bits(u32 bits){ union{u32 u; float f;} v; v.u=bits; return v.f; }
__device__ __forceinline__ float bf_lo(u32 w){ return b2f_bits(w<<16); }
__device__ __forceinline__ float bf_hi(u32 w){ return b2f_bits(w & 0xffff0000u); }
__device__ __forceinline__ u16 f2bf(float f){
  union{float f; u32 u;} v; v.f=f;
  return (u16)((v.u + 0x7fffu + ((v.u>>16)&1u))>>16);   // round-to-nearest-even
}

// ---------------- graph build ----------------

// detect int64-vs-int32 edge layout AND zero the bucket cursors (fused)
__global__ void detect_k(const long long* __restrict__ ei, int* __restrict__ flag,
                         int* __restrict__ gcur, int n, int E, int nbuck){
  __shared__ int sh[256];
  int t = threadIdx.x;
  for(int i=t; i<nbuck; i+=256) gcur[i]=0;
  int lim = E/2 < 2048 ? E/2 : 2048;
  int bad = 0;
  for(int e=t; e<lim; e+=256){
    unsigned long long v = (unsigned long long)ei[e];
    if(v >= (unsigned long long)n) bad = 1;
  }
  sh[t]=bad; __syncthreads();
  for(int off=128; off>0; off>>=1){ if(t<off) sh[t] |= sh[t+off]; __syncthreads(); }
  if(t==0) *flag = sh[0];   // 1 => data is int32
}

__device__ __forceinline__ int edge_at(const void* eiv, int is32, long long idx){
  return is32 ? ((const int*)eiv)[idx] : (int)((const long long*)eiv)[idx];
}
__device__ __forceinline__ int clampi(int v, int lo, int hi){
  return v < lo ? lo : (v > hi ? hi : v);
}

// pass A: tile-level counting sort into coarse buckets (row>>7), pairs (r&127)<<17 | c
__global__ __launch_bounds__(256) void binA_k(const void* __restrict__ eiv, const int* __restrict__ flag,
                        int* __restrict__ gcur, u32* __restrict__ gbuf, int E, int n, int nbuck){
  __shared__ int hist[1024];
  __shared__ int base[1024];
  __shared__ int cur[1024];
  __shared__ int wsum[256];
  __shared__ u32 stage[TILE];
  int t = threadIdx.x;
  long long e0 = (long long)blockIdx.x * TILE;
  int cnt = (int)((long long)E - e0 < TILE ? (long long)E - e0 : TILE);
  int is32 = *flag;
  for(int i=t; i<nbuck; i+=256){ hist[i]=0; cur[i]=0; }
  __syncthreads();
  int eb[16]; u32 ep[16]; int ec=0;
  #pragma unroll
  for(int k=0;k<16;k++){
    int i = t + k*256;
    if(i<cnt){
      long long e = e0 + i;
      int r = clampi(edge_at(eiv,is32,e),0,n-1);
      int c = clampi(edge_at(eiv,is32,(long long)E+e),0,n-1);
      eb[ec] = r>>7;
      ep[ec] = ((u32)(r&127)<<17) | (u32)c;
      atomicAdd(&hist[eb[ec]],1);
      ec++;
    }
  }
  __syncthreads();
  int l[4]; int tot=0;
  #pragma unroll
  for(int j=0;j<4;j++){ int idx=t*4+j; l[j]=(idx<nbuck)?hist[idx]:0; tot+=l[j]; }
  wsum[t]=tot; __syncthreads();
  for(int off=1;off<256;off<<=1){
    int x = (t>=off)?wsum[t-off]:0;
    __syncthreads();
    wsum[t]+=x;
    __syncthreads();
  }
  int excl = wsum[t]-tot;
  #pragma unroll
  for(int j=0;j<4;j++){ int idx=t*4+j; if(idx<nbuck) base[idx]=excl; excl+=l[j]; }
  __syncthreads();
  for(int k=0;k<ec;k++){
    int b = eb[k];
    int slot = base[b] + atomicAdd(&cur[b],1);
    stage[slot] = ep[k];
  }
  __syncthreads();
  for(int b=t; b<nbuck; b+=256){
    int c = hist[b];
    if(c>0){
      int g = atomicAdd(&gcur[b], c);
      if(g > CAP) g = CAP;
      if(g + c > CAP) c = CAP - g;
      int src = base[b];
      u32* dst = gbuf + (size_t)b*CAP + g;
      for(int k=0;k<c;k++) dst[k] = stage[src+k];
    }
  }
}

// scan of per-bucket counts -> global bucket starts (one block)
__global__ __launch_bounds__(256) void scanG_k(const int* __restrict__ gcnt, int* __restrict__ gstart, int nbuck){
  __shared__ int sh[256];
  int t = threadIdx.x;
  int v[4]; int s=0;
  #pragma unroll
  for(int j=0;j<4;j++){
    int idx=t*4+j;
    int c = (idx<nbuck)?gcnt[idx]:0;
    if(c>CAP) c=CAP;
    v[j]=c; s+=c;
  }
  sh[t]=s; __syncthreads();
  for(int off=1;off<256;off<<=1){
    int x=(t>=off)?sh[t-off]:0;
    __syncthreads();
    sh[t]+=x;
    __syncthreads();
  }
  int excl = sh[t]-s;
  #pragma unroll
  for(int j=0;j<4;j++){ int idx=t*4+j; if(idx<nbuck) gstart[idx]=excl; excl+=v[j]; }
}

// pass B (fused): per-bucket degree + local scan + deg/dinv/rs outputs + CSR materialization
__global__ __launch_bounds__(256) void csrB_k(const int* __restrict__ gcnt, const int* __restrict__ gstart,
                        const u32* __restrict__ gbuf, int* __restrict__ deg, float* __restrict__ dinv,
                        int* __restrict__ rs, int* __restrict__ csr, int n, int nbuck){
  __shared__ int h[128], lst[128], lcur[128], sc[128];
  __shared__ int colstage[CAP];
  int b = blockIdx.x, t = threadIdx.x;
  if(t<128){ h[t]=0; lcur[t]=0; }
  __syncthreads();
  int c = gcnt[b]; if(c>CAP) c=CAP;
  const u32* p = gbuf + (size_t)b*CAP;
  for(int i=t;i<c;i+=256) atomicAdd(&h[p[i]>>17],1);
  __syncthreads();
  int dv=0;
  if(t<128){ dv=h[t]; sc[t]=dv; }
  __syncthreads();
  for(int off=1;off<128;off<<=1){
    int x=(t>=off&&t<128)?sc[t-off]:0;
    __syncthreads();
    if(t<128) sc[t]+=x;
    __syncthreads();
  }
  int g0 = gstart[b];
  if(t<128){
    lst[t]=sc[t]-dv;
    int row=b*128+t;
    if(row<n){
      deg[row]=dv;
      dinv[row]=rsqrtf((float)(dv+1));   // +1: self loop
      rs[row]=g0+lst[t];
    }
  }
  __syncthreads();
  for(int i=t;i<c;i+=256){
    u32 pr=p[i];
    int rl=pr>>17;
    int slot=lst[rl]+atomicAdd(&lcur[rl],1);
    if(slot<CAP) colstage[slot]=(int)(pr&0x1FFFFu);
  }
  __syncthreads();
  for(int i=t;i<c;i+=256) csr[g0+i]=colstage[i];
}

// ---------------- weights prep ----------------
// pack fp32 [256][256] W1,W2 into MFMA B-fragment order: [kk(8)][ct(16)][lane(64)][j(8)] bf16
__global__ void pack2_k(const float* __restrict__ W1, const float* __restrict__ W2,
                        u16* __restrict__ o1, u16* __restrict__ o2){
  int bid = blockIdx.x;
  const float* W = (bid<256)? W1 : W2;
  u16* out = (bid<256)? o1 : o2;
  int idx = (bid&255)*256 + threadIdx.x;   // 65536 per matrix
  int j  = idx & 7;
  int l  = (idx>>3) & 63;
  int ct = (idx>>9) & 15;
  int kk = idx>>13;
  int k  = kk*32 + (l>>4)*8 + j;
  int nn = ct*16 + (l&15);
  out[idx] = f2bf(W[k*256 + nn]);
}

// ---------------- propagate (3-wide, fp32) ----------------
__global__ void prop3_k(const float* __restrict__ x, const int* __restrict__ csr,
                        const int* __restrict__ rs, const int* __restrict__ deg,
                        const float* __restrict__ dinv, float* __restrict__ p0, int n){
  int i = blockIdx.x*256 + threadIdx.x;
  if(i>=n) return;
  float a0=0.f, a1=0.f, a2=0.f;
  int s = rs[i], e = s + deg[i];
  for(int t=s; t<e; t++){
    int c = csr[t];
    float w = dinv[c];
    a0 += w*x[c*3+0]; a1 += w*x[c*3+1]; a2 += w*x[c*3+2];
  }
  float di = dinv[i];
  a0 += di*x[i*3+0]; a1 += di*x[i*3+1]; a2 += di*x[i*3+2];
  p0[i*3+0]=di*a0; p0[i*3+1]=di*a1; p0[i*3+2]=di*a2;
}

// ---------------- propagate (256-wide bf16): 2 rows per wave, uint4 per lane ----------------
// half-wave per row: 32 lanes x 16B = 512B row; 8 outstanding 16B loads per lane,
// 2 independent row streams per wave.
__global__ __launch_bounds__(256) void prop2x_k(const u16* __restrict__ hin, u16* __restrict__ pout,
                          const int* __restrict__ csr, const int* __restrict__ rs,
                          const int* __restrict__ deg, const float* __restrict__ dinv, int n){
  int pair = (blockIdx.x*256 + threadIdx.x) >> 6;
  int r0 = pair*2;
  if(r0>=n) return;
  int lane = threadIdx.x & 63;
  int half = lane>>5;
  int li = lane & 31;
  int row = r0 + half;
  int rok = row < n;
  int rowc = rok ? row : r0;
  const u16* hb = hin + li*8;
  uint4 sv = *(const uint4*)(hb + (size_t)rowc*256);
  float a[8];
  a[0]=bf_lo(sv.x); a[1]=bf_hi(sv.x); a[2]=bf_lo(sv.y); a[3]=bf_hi(sv.y);
  a[4]=bf_lo(sv.z); a[5]=bf_hi(sv.z); a[6]=bf_lo(sv.w); a[7]=bf_hi(sv.w);
  int s = rs[rowc];
  int d = rok ? deg[rowc] : 0;
  int dmax = max(d, __shfl_xor(d, 32));
  for(int base=0; base<dmax; base+=8){
    int cc[8]; u32 mk[8];
    #pragma unroll
    for(int j=0;j<8;j++){
      int ok = (base+j) < d;
      cc[j] = csr[ok ? (s+base+j) : s];
      mk[j] = ok ? 0xffffffffu : 0u;
    }
    uint4 v[8];
    #pragma unroll
    for(int j=0;j<8;j++) v[j] = *(const uint4*)(hb + (size_t)cc[j]*256);
    #pragma unroll
    for(int j=0;j<8;j++){
      u32 w0=v[j].x&mk[j], w1=v[j].y&mk[j], w2=v[j].z&mk[j], w3=v[j].w&mk[j];
      a[0]+=bf_lo(w0); a[1]+=bf_hi(w0); a[2]+=bf_lo(w1); a[3]+=bf_hi(w1);
      a[4]+=bf_lo(w2); a[5]+=bf_hi(w2); a[6]+=bf_lo(w3); a[7]+=bf_hi(w3);
    }
  }
  if(rok){
    float sc = dinv[row];
    uint4 o;
    o.x=(u32)f2bf(a[0]*sc)|((u32)f2bf(a[1]*sc)<<16);
    o.y=(u32)f2bf(a[2]*sc)|((u32)f2bf(a[3]*sc)<<16);
    o.z=(u32)f2bf(a[4]*sc)|((u32)f2bf(a[5]*sc)<<16);
    o.w=(u32)f2bf(a[6]*sc)|((u32)f2bf(a[7]*sc)<<16);
    *(uint4*)(pout + (size_t)row*256 + li*8) = o;
  }
}

// ---------------- GEMMs ----------------
__global__ __launch_bounds__(256) void gemm0_k(const float* __restrict__ p0, const float* __restrict__ W0,
                        const float* __restrict__ b0, const float* __restrict__ dinv,
                        u16* __restrict__ h1, int n){
  int i = blockIdx.x;
  int j = threadIdx.x;
  float v = p0[i*3+0]*W0[j] + p0[i*3+1]*W0[256+j] + p0[i*3+2]*W0[512+j] + b0[j];
  v = fmaxf(v, 0.f) * dinv[i];
  h1[(size_t)i*256 + j] = f2bf(v);
}

__global__ __launch_bounds__(256) void gemm256_k(const u16* __restrict__ A, const u16* __restrict__ Bp,
                          const float* __restrict__ bias, const float* __restrict__ dinv,
                          u16* __restrict__ Out, int M){
  int wave = threadIdx.x>>6, lane = threadIdx.x&63;
  int rowbase = blockIdx.x*64 + wave*16;
  f32x4 acc[16];
  #pragma unroll
  for(int t=0;t<16;t++){ acc[t][0]=0.f; acc[t][1]=0.f; acc[t][2]=0.f; acc[t][3]=0.f; }
  const u16* Ap = A + (size_t)(rowbase + (lane&15))*256 + ((lane>>4)*8);
  const u16* Bl = Bp + (size_t)lane*8;
  #pragma unroll
  for(int kk=0; kk<8; kk++){
    short8 af = *(const short8*)(Ap + kk*32);
    const u16* bb = Bl + (size_t)kk*8192;
    #pragma unroll
    for(int t=0;t<16;t++){
      short8 bf = *(const short8*)(bb + t*512);
      acc[t] = __builtin_amdgcn_mfma_f32_16x16x32_bf16(af, bf, acc[t], 0, 0, 0);
    }
  }
  int r0 = rowbase + (lane>>4)*4;
  float dv[4]; bool ok[4];
  #pragma unroll
  for(int r=0;r<4;r++){ ok[r] = (r0+r) < M; dv[r] = ok[r] ? dinv[r0+r] : 0.f; }
  #pragma unroll
  for(int t=0;t<16;t++){
    int col = t*16 + (lane&15);
    float bc = bias[col];
    #pragma unroll
    for(int r=0;r<4;r++){
      if(ok[r]){
        float v = fmaxf(acc[t][r] + bc, 0.f) * dv[r];
        Out[(size_t)(r0+r)*256 + col] = f2bf(v);
      }
    }
  }
}

__global__ __launch_bounds__(256) void gemm3_k(const u16* __restrict__ h3, const float* __restrict__ W3,
                        float* __restrict__ qh, int n){
  __shared__ float w3s[768];
  for(int i=threadIdx.x; i<768; i+=256) w3s[i] = W3[i];
  __syncthreads();
  int i = blockIdx.x*256 + threadIdx.x;
  if(i>=n) return;
  float a0=0.f, a1=0.f, a2=0.f;
  const uint4* hp = (const uint4*)(h3 + (size_t)i*256);
  for(int kk=0; kk<32; kk++){
    uint4 v = hp[kk];
    float f[8] = {bf_lo(v.x),bf_hi(v.x),bf_lo(v.y),bf_hi(v.y),
                  bf_lo(v.z),bf_hi(v.z),bf_lo(v.w),bf_hi(v.w)};
    int k0 = kk*8;
    #pragma unroll
    for(int j=0;j<8;j++){
      a0 += f[j]*w3s[(k0+j)*3+0];
      a1 += f[j]*w3s[(k0+j)*3+1];
      a2 += f[j]*w3s[(k0+j)*3+2];
    }
  }
  qh[i*3+0]=a0; qh[i*3+1]=a1; qh[i*3+2]=a2;
}

__global__ void final_k(const float* __restrict__ qh, const float* __restrict__ x,
                        const int* __restrict__ csr, const int* __restrict__ rs,
                        const int* __restrict__ deg, const float* __restrict__ dinv,
                        const float* __restrict__ b3, const float* __restrict__ Wr,
                        const float* __restrict__ br, float* __restrict__ out, int n){
  int i = blockIdx.x*256 + threadIdx.x;
  if(i>=n) return;
  float a0=0.f, a1=0.f, a2=0.f;
  int s = rs[i], e = s + deg[i];
  for(int t=s; t<e; t++){
    int c = csr[t];
    a0 += qh[c*3+0]; a1 += qh[c*3+1]; a2 += qh[c*3+2];
  }
  float di = dinv[i];
  a0 = di*(a0 + qh[i*3+0]);
  a1 = di*(a1 + qh[i*3+1]);
  a2 = di*(a2 + qh[i*3+2]);
  float x0=x[i*3+0], x1=x[i*3+1], x2=x[i*3+2];
  out[i*3+0] = a0 + b3[0] + x0*Wr[0] + x1*Wr[3] + x2*Wr[6] + br[0];
  out[i*3+1] = a1 + b3[1] + x0*Wr[1] + x1*Wr[4] + x2*Wr[7] + br[1];
  out[i*3+2] = a2 + b3[2] + x0*Wr[2] + x1*Wr[5] + x2*Wr[8] + br[2];
}

// ---------------- launch ----------------
extern "C" void kernel_launch(void* const* d_in, const int* in_sizes, int n_in,
                              void* d_out, int out_size, void* d_ws, size_t ws_size,
                              hipStream_t stream) {
  const float* x  = (const float*)d_in[0];
  const void*  ei = d_in[1];
  const float* W0 = (const float*)d_in[2];
  const float* b0 = (const float*)d_in[3];
  const float* W1 = (const float*)d_in[4];
  const float* b1 = (const float*)d_in[5];
  const float* W2 = (const float*)d_in[6];
  const float* b2 = (const float*)d_in[7];
  const float* W3 = (const float*)d_in[8];
  const float* b3 = (const float*)d_in[9];
  const float* Wr = (const float*)d_in[10];
  const float* br = (const float*)d_in[11];
  float* out = (float*)d_out;

  int n = in_sizes[0]/3;
  int E = in_sizes[1]/2;
  int nbuck = (n+127)>>7;              // 128 rows per bucket
  int Mpad = ((n+63)/64)*64;

  char* p = (char*)d_ws;
  auto alloc = [&](size_t bytes)->char*{ char* r=p; p += (bytes+255)&~(size_t)255; return r; };
  int*   gcur  = (int*)  alloc((size_t)nbuck*4);
  int*   gstart= (int*)  alloc((size_t)nbuck*4);
  int*   deg   = (int*)  alloc((size_t)n*4);
  float* dinv  = (float*)alloc((size_t)n*4);
  int*   rs    = (int*)  alloc((size_t)n*4);
  int*   flag  = (int*)  alloc(256);
  int*   csr   = (int*)  alloc((size_t)E*4);
  u16*   hA    = (u16*)  alloc((size_t)Mpad*512);
  u16*   hB    = (u16*)  alloc((size_t)Mpad*512);
  float* p0    = (float*)alloc((size_t)n*12);
  float* qh    = (float*)alloc((size_t)n*12);
  u16*   W1p   = (u16*)  alloc(65536*2);
  u16*   W2p   = (u16*)  alloc(65536*2);
  // gbuf (nbuck*CAP*4 ~ 19.2MB) aliases hA (51.2MB): dead before gemm0 writes hA
  u32*   gbuf  = (u32*)hA;

  int gn  = (n+255)/256;
  int gA  = (E+TILE-1)/TILE;
  int gp2 = (((n+1)/2)*64 + 255)/256;  // prop grid: one wave per row-PAIR

  // graph build: 2-pass LDS-staged counting sort, fused metadata
  detect_k<<<1, 256, 0, stream>>>((const long long*)ei, flag, gcur, n, E, nbuck);
  binA_k  <<<gA, 256, 0, stream>>>(ei, flag, gcur, gbuf, E, n, nbuck);
  scanG_k <<<1, 256, 0, stream>>>(gcur, gstart, nbuck);
  csrB_k  <<<nbuck, 256, 0, stream>>>(gcur, gstart, gbuf, deg, dinv, rs, csr, n, nbuck);

  // weights
  pack2_k <<<512, 256, 0, stream>>>(W1, W2, W1p, W2p);

  // layer 0
  prop3_k <<<gn, 256, 0, stream>>>(x, csr, rs, deg, dinv, p0, n);
  gemm0_k <<<n, 256, 0, stream>>>(p0, W0, b0, dinv, hA, n);

  // layer 1
  prop2x_k<<<gp2, 256, 0, stream>>>(hA, hB, csr, rs, deg, dinv, n);
  gemm256_k<<<Mpad/64, 256, 0, stream>>>(hB, W1p, b1, dinv, hA, n);

  // layer 2
  prop2x_k<<<gp2, 256, 0, stream>>>(hA, hB, csr, rs, deg, dinv, n);
  gemm256_k<<<Mpad/64, 256, 0, stream>>>(hB, W2p, b2, dinv, hA, n);

  // layer 3 + skip
  gemm3_k <<<gn, 256, 0, stream>>>(hA, W3, qh, n);
  final_k <<<gn, 256, 0, stream>>>(qh, x, csr, rs, deg, dinv, b3, Wr, br, out, n);
}

// Round 9
// 878.967 us; speedup vs baseline: 1.4819x; 1.0314x over previous
//
#include <hip/hip_runtime.h>
#include <stdint.h>

typedef unsigned short u16;
typedef unsigned int u32;
typedef __attribute__((ext_vector_type(8))) short short8;
typedef __attribute__((ext_vector_type(4))) float f32x4;
typedef __attribute__((ext_vector_type(2))) unsigned int u32x2;

#define CAP 6144        // pairs per coarse bucket region (mean ~4096, +32 sigma margin)
#define TILE 4096       // edges per binA block

__device__ __forceinline__ float b2f_bits(u32 bits){ union{u32 u; float f;} v; v.u=bits; return v.f; }
__device__ __forceinline__ float bf_lo(u32 w){ return b2f_bits(w<<16); }
__device__ __forceinline__ float bf_hi(u32 w){ return b2f_bits(w & 0xffff0000u); }
__device__ __forceinline__ u16 f2bf(float f){
  union{float f; u32 u;} v; v.f=f;
  return (u16)((v.u + 0x7fffu + ((v.u>>16)&1u))>>16);   // round-to-nearest-even
}

// ---------------- graph build ----------------

// detect int64-vs-int32 edge layout AND zero the bucket cursors (fused)
__global__ void detect_k(const long long* __restrict__ ei, int* __restrict__ flag,
                         int* __restrict__ gcur, int n, int E, int nbuck){
  __shared__ int sh[256];
  int t = threadIdx.x;
  for(int i=t; i<nbuck; i+=256) gcur[i]=0;
  int lim = E/2 < 2048 ? E/2 : 2048;
  int bad = 0;
  for(int e=t; e<lim; e+=256){
    unsigned long long v = (unsigned long long)ei[e];
    if(v >= (unsigned long long)n) bad = 1;
  }
  sh[t]=bad; __syncthreads();
  for(int off=128; off>0; off>>=1){ if(t<off) sh[t] |= sh[t+off]; __syncthreads(); }
  if(t==0) *flag = sh[0];   // 1 => data is int32
}

__device__ __forceinline__ int edge_at(const void* eiv, int is32, long long idx){
  return is32 ? ((const int*)eiv)[idx] : (int)((const long long*)eiv)[idx];
}
__device__ __forceinline__ int clampi(int v, int lo, int hi){
  return v < lo ? lo : (v > hi ? hi : v);
}

// pass A: tile-level counting sort into coarse buckets (row>>7), pairs (r&127)<<17 | c
__global__ __launch_bounds__(256) void binA_k(const void* __restrict__ eiv, const int* __restrict__ flag,
                        int* __restrict__ gcur, u32* __restrict__ gbuf, int E, int n, int nbuck){
  __shared__ int hist[1024];
  __shared__ int base[1024];
  __shared__ int cur[1024];
  __shared__ int wsum[256];
  __shared__ u32 stage[TILE];
  int t = threadIdx.x;
  long long e0 = (long long)blockIdx.x * TILE;
  int cnt = (int)((long long)E - e0 < TILE ? (long long)E - e0 : TILE);
  int is32 = *flag;
  for(int i=t; i<nbuck; i+=256){ hist[i]=0; cur[i]=0; }
  __syncthreads();
  int eb[16]; u32 ep[16]; int ec=0;
  #pragma unroll
  for(int k=0;k<16;k++){
    int i = t + k*256;
    if(i<cnt){
      long long e = e0 + i;
      int r = clampi(edge_at(eiv,is32,e),0,n-1);
      int c = clampi(edge_at(eiv,is32,(long long)E+e),0,n-1);
      eb[ec] = r>>7;
      ep[ec] = ((u32)(r&127)<<17) | (u32)c;
      atomicAdd(&hist[eb[ec]],1);
      ec++;
    }
  }
  __syncthreads();
  int l[4]; int tot=0;
  #pragma unroll
  for(int j=0;j<4;j++){ int idx=t*4+j; l[j]=(idx<nbuck)?hist[idx]:0; tot+=l[j]; }
  wsum[t]=tot; __syncthreads();
  for(int off=1;off<256;off<<=1){
    int x = (t>=off)?wsum[t-off]:0;
    __syncthreads();
    wsum[t]+=x;
    __syncthreads();
  }
  int excl = wsum[t]-tot;
  #pragma unroll
  for(int j=0;j<4;j++){ int idx=t*4+j; if(idx<nbuck) base[idx]=excl; excl+=l[j]; }
  __syncthreads();
  for(int k=0;k<ec;k++){
    int b = eb[k];
    int slot = base[b] + atomicAdd(&cur[b],1);
    stage[slot] = ep[k];
  }
  __syncthreads();
  for(int b=t; b<nbuck; b+=256){
    int c = hist[b];
    if(c>0){
      int g = atomicAdd(&gcur[b], c);
      if(g > CAP) g = CAP;
      if(g + c > CAP) c = CAP - g;
      int src = base[b];
      u32* dst = gbuf + (size_t)b*CAP + g;
      for(int k=0;k<c;k++) dst[k] = stage[src+k];
    }
  }
}

// scan of per-bucket counts -> global bucket starts (one block)
__global__ __launch_bounds__(256) void scanG_k(const int* __restrict__ gcnt, int* __restrict__ gstart, int nbuck){
  __shared__ int sh[256];
  int t = threadIdx.x;
  int v[4]; int s=0;
  #pragma unroll
  for(int j=0;j<4;j++){
    int idx=t*4+j;
    int c = (idx<nbuck)?gcnt[idx]:0;
    if(c>CAP) c=CAP;
    v[j]=c; s+=c;
  }
  sh[t]=s; __syncthreads();
  for(int off=1;off<256;off<<=1){
    int x=(t>=off)?sh[t-off]:0;
    __syncthreads();
    sh[t]+=x;
    __syncthreads();
  }
  int excl = sh[t]-s;
  #pragma unroll
  for(int j=0;j<4;j++){ int idx=t*4+j; if(idx<nbuck) gstart[idx]=excl; excl+=v[j]; }
}

// pass B (fused): per-bucket degree + local scan + deg/dinv/rs outputs + CSR materialization
__global__ __launch_bounds__(256) void csrB_k(const int* __restrict__ gcnt, const int* __restrict__ gstart,
                        const u32* __restrict__ gbuf, int* __restrict__ deg, float* __restrict__ dinv,
                        int* __restrict__ rs, int* __restrict__ csr, int n, int nbuck){
  __shared__ int h[128], lst[128], lcur[128], sc[128];
  __shared__ int colstage[CAP];
  int b = blockIdx.x, t = threadIdx.x;
  if(t<128){ h[t]=0; lcur[t]=0; }
  __syncthreads();
  int c = gcnt[b]; if(c>CAP) c=CAP;
  const u32* p = gbuf + (size_t)b*CAP;
  for(int i=t;i<c;i+=256) atomicAdd(&h[p[i]>>17],1);
  __syncthreads();
  int dv=0;
  if(t<128){ dv=h[t]; sc[t]=dv; }
  __syncthreads();
  for(int off=1;off<128;off<<=1){
    int x=(t>=off&&t<128)?sc[t-off]:0;
    __syncthreads();
    if(t<128) sc[t]+=x;
    __syncthreads();
  }
  int g0 = gstart[b];
  if(t<128){
    lst[t]=sc[t]-dv;
    int row=b*128+t;
    if(row<n){
      deg[row]=dv;
      dinv[row]=rsqrtf((float)(dv+1));   // +1: self loop
      rs[row]=g0+lst[t];
    }
  }
  __syncthreads();
  for(int i=t;i<c;i+=256){
    u32 pr=p[i];
    int rl=pr>>17;
    int slot=lst[rl]+atomicAdd(&lcur[rl],1);
    if(slot<CAP) colstage[slot]=(int)(pr&0x1FFFFu);
  }
  __syncthreads();
  for(int i=t;i<c;i+=256) csr[g0+i]=colstage[i];
}

// ---------------- weights prep ----------------
// pack fp32 [256][256] W1,W2 into MFMA B-fragment order: [kk(8)][ct(16)][lane(64)][j(8)] bf16
__global__ void pack2_k(const float* __restrict__ W1, const float* __restrict__ W2,
                        u16* __restrict__ o1, u16* __restrict__ o2){
  int bid = blockIdx.x;
  const float* W = (bid<256)? W1 : W2;
  u16* out = (bid<256)? o1 : o2;
  int idx = (bid&255)*256 + threadIdx.x;   // 65536 per matrix
  int j  = idx & 7;
  int l  = (idx>>3) & 63;
  int ct = (idx>>9) & 15;
  int kk = idx>>13;
  int k  = kk*32 + (l>>4)*8 + j;
  int nn = ct*16 + (l&15);
  out[idx] = f2bf(W[k*256 + nn]);
}

// ---------------- propagate (3-wide, fp32) ----------------
__global__ void prop3_k(const float* __restrict__ x, const int* __restrict__ csr,
                        const int* __restrict__ rs, const int* __restrict__ deg,
                        const float* __restrict__ dinv, float* __restrict__ p0, int n){
  int i = blockIdx.x*256 + threadIdx.x;
  if(i>=n) return;
  float a0=0.f, a1=0.f, a2=0.f;
  int s = rs[i], e = s + deg[i];
  for(int t=s; t<e; t++){
    int c = csr[t];
    float w = dinv[c];
    a0 += w*x[c*3+0]; a1 += w*x[c*3+1]; a2 += w*x[c*3+2];
  }
  float di = dinv[i];
  a0 += di*x[i*3+0]; a1 += di*x[i*3+1]; a2 += di*x[i*3+2];
  p0[i*3+0]=di*a0; p0[i*3+1]=di*a1; p0[i*3+2]=di*a2;
}

// ---------------- propagate (256-wide bf16, one wave/row, 16 gathers in flight) ----------------
// nontemporal output store: don't let the 50MB streaming write evict gather lines from L2
__global__ __launch_bounds__(256) void prop256_k(const u16* __restrict__ hin, u16* __restrict__ pout,
                          const int* __restrict__ csr, const int* __restrict__ rs,
                          const int* __restrict__ deg, const float* __restrict__ dinv, int n){
  int row = (blockIdx.x*256 + threadIdx.x) >> 6;
  if(row>=n) return;
  row = __builtin_amdgcn_readfirstlane(row);
  int lane = threadIdx.x & 63;
  int co = lane*4;
  const u16* hb = hin + co;
  uint2 sv = *(const uint2*)(hb + (size_t)row*256);
  float a0=bf_lo(sv.x), a1=bf_hi(sv.x), a2=bf_lo(sv.y), a3=bf_hi(sv.y);
  int s = __builtin_amdgcn_readfirstlane(rs[row]);
  int d = __builtin_amdgcn_readfirstlane(deg[row]);
  for(int base=0; base<d; base+=16){
    int cc[16]; u32 mk[16];
    #pragma unroll
    for(int j=0;j<16;j++){
      int ok = (base+j) < d;                 // wave-uniform
      cc[j] = csr[ok ? (s+base+j) : s];
      mk[j] = ok ? 0xffffffffu : 0u;
    }
    uint2 v[16];
    #pragma unroll
    for(int j=0;j<16;j++) v[j] = *(const uint2*)(hb + (size_t)cc[j]*256);
    #pragma unroll
    for(int j=0;j<16;j++){
      u32 xw = v[j].x & mk[j], yw = v[j].y & mk[j];
      a0 += bf_lo(xw); a1 += bf_hi(xw); a2 += bf_lo(yw); a3 += bf_hi(yw);
    }
  }
  float sc = dinv[row];
  u32x2 o;
  o.x = (u32)f2bf(a0*sc) | ((u32)f2bf(a1*sc)<<16);
  o.y = (u32)f2bf(a2*sc) | ((u32)f2bf(a3*sc)<<16);
  __builtin_nontemporal_store(o, (u32x2*)(pout + (size_t)row*256 + co));
}

// ---------------- GEMMs ----------------
__global__ __launch_bounds__(256) void gemm0_k(const float* __restrict__ p0, const float* __restrict__ W0,
                        const float* __restrict__ b0, const float* __restrict__ dinv,
                        u16* __restrict__ h1, int n){
  int i = blockIdx.x;
  int j = threadIdx.x;
  float v = p0[i*3+0]*W0[j] + p0[i*3+1]*W0[256+j] + p0[i*3+2]*W0[512+j] + b0[j];
  v = fmaxf(v, 0.f) * dinv[i];
  h1[(size_t)i*256 + j] = f2bf(v);
}

__global__ __launch_bounds__(256) void gemm256_k(const u16* __restrict__ A, const u16* __restrict__ Bp,
                          const float* __restrict__ bias, const float* __restrict__ dinv,
                          u16* __restrict__ Out, int M){
  int wave = threadIdx.x>>6, lane = threadIdx.x&63;
  int rowbase = blockIdx.x*64 + wave*16;
  f32x4 acc[16];
  #pragma unroll
  for(int t=0;t<16;t++){ acc[t][0]=0.f; acc[t][1]=0.f; acc[t][2]=0.f; acc[t][3]=0.f; }
  const u16* Ap = A + (size_t)(rowbase + (lane&15))*256 + ((lane>>4)*8);
  const u16* Bl = Bp + (size_t)lane*8;
  #pragma unroll
  for(int kk=0; kk<8; kk++){
    short8 af = __builtin_nontemporal_load((const short8*)(Ap + kk*32));   // streaming, read-once
    const u16* bb = Bl + (size_t)kk*8192;
    #pragma unroll
    for(int t=0;t<16;t++){
      short8 bf = *(const short8*)(bb + t*512);
      acc[t] = __builtin_amdgcn_mfma_f32_16x16x32_bf16(af, bf, acc[t], 0, 0, 0);
    }
  }
  int r0 = rowbase + (lane>>4)*4;
  float dv[4]; bool ok[4];
  #pragma unroll
  for(int r=0;r<4;r++){ ok[r] = (r0+r) < M; dv[r] = ok[r] ? dinv[r0+r] : 0.f; }
  #pragma unroll
  for(int t=0;t<16;t++){
    int col = t*16 + (lane&15);
    float bc = bias[col];
    #pragma unroll
    for(int r=0;r<4;r++){
      if(ok[r]){
        float v = fmaxf(acc[t][r] + bc, 0.f) * dv[r];
        Out[(size_t)(r0+r)*256 + col] = f2bf(v);
      }
    }
  }
}

__global__ __launch_bounds__(256) void gemm3_k(const u16* __restrict__ h3, const float* __restrict__ W3,
                        float* __restrict__ qh, int n){
  __shared__ float w3s[768];
  for(int i=threadIdx.x; i<768; i+=256) w3s[i] = W3[i];
  __syncthreads();
  int i = blockIdx.x*256 + threadIdx.x;
  if(i>=n) return;
  float a0=0.f, a1=0.f, a2=0.f;
  const uint4* hp = (const uint4*)(h3 + (size_t)i*256);
  for(int kk=0; kk<32; kk++){
    uint4 v = hp[kk];
    float f[8] = {bf_lo(v.x),bf_hi(v.x),bf_lo(v.y),bf_hi(v.y),
                  bf_lo(v.z),bf_hi(v.z),bf_lo(v.w),bf_hi(v.w)};
    int k0 = kk*8;
    #pragma unroll
    for(int j=0;j<8;j++){
      a0 += f[j]*w3s[(k0+j)*3+0];
      a1 += f[j]*w3s[(k0+j)*3+1];
      a2 += f[j]*w3s[(k0+j)*3+2];
    }
  }
  qh[i*3+0]=a0; qh[i*3+1]=a1; qh[i*3+2]=a2;
}

__global__ void final_k(const float* __restrict__ qh, const float* __restrict__ x,
                        const int* __restrict__ csr, const int* __restrict__ rs,
                        const int* __restrict__ deg, const float* __restrict__ dinv,
                        const float* __restrict__ b3, const float* __restrict__ Wr,
                        const float* __restrict__ br, float* __restrict__ out, int n){
  int i = blockIdx.x*256 + threadIdx.x;
  if(i>=n) return;
  float a0=0.f, a1=0.f, a2=0.f;
  int s = rs[i], e = s + deg[i];
  for(int t=s; t<e; t++){
    int c = csr[t];
    a0 += qh[c*3+0]; a1 += qh[c*3+1]; a2 += qh[c*3+2];
  }
  float di = dinv[i];
  a0 = di*(a0 + qh[i*3+0]);
  a1 = di*(a1 + qh[i*3+1]);
  a2 = di*(a2 + qh[i*3+2]);
  float x0=x[i*3+0], x1=x[i*3+1], x2=x[i*3+2];
  out[i*3+0] = a0 + b3[0] + x0*Wr[0] + x1*Wr[3] + x2*Wr[6] + br[0];
  out[i*3+1] = a1 + b3[1] + x0*Wr[1] + x1*Wr[4] + x2*Wr[7] + br[1];
  out[i*3+2] = a2 + b3[2] + x0*Wr[2] + x1*Wr[5] + x2*Wr[8] + br[2];
}

// ---------------- launch ----------------
extern "C" void kernel_launch(void* const* d_in, const int* in_sizes, int n_in,
                              void* d_out, int out_size, void* d_ws, size_t ws_size,
                              hipStream_t stream) {
  const float* x  = (const float*)d_in[0];
  const void*  ei = d_in[1];
  const float* W0 = (const float*)d_in[2];
  const float* b0 = (const float*)d_in[3];
  const float* W1 = (const float*)d_in[4];
  const float* b1 = (const float*)d_in[5];
  const float* W2 = (const float*)d_in[6];
  const float* b2 = (const float*)d_in[7];
  const float* W3 = (const float*)d_in[8];
  const float* b3 = (const float*)d_in[9];
  const float* Wr = (const float*)d_in[10];
  const float* br = (const float*)d_in[11];
  float* out = (float*)d_out;

  int n = in_sizes[0]/3;
  int E = in_sizes[1]/2;
  int nbuck = (n+127)>>7;              // 128 rows per bucket
  int Mpad = ((n+63)/64)*64;

  char* p = (char*)d_ws;
  auto alloc = [&](size_t bytes)->char*{ char* r=p; p += (bytes+255)&~(size_t)255; return r; };
  int*   gcur  = (int*)  alloc((size_t)nbuck*4);
  int*   gstart= (int*)  alloc((size_t)nbuck*4);
  int*   deg   = (int*)  alloc((size_t)n*4);
  float* dinv  = (float*)alloc((size_t)n*4);
  int*   rs    = (int*)  alloc((size_t)n*4);
  int*   flag  = (int*)  alloc(256);
  int*   csr   = (int*)  alloc((size_t)E*4);
  u16*   hA    = (u16*)  alloc((size_t)Mpad*512);
  u16*   hB    = (u16*)  alloc((size_t)Mpad*512);
  float* p0    = (float*)alloc((size_t)n*12);
  float* qh    = (float*)alloc((size_t)n*12);
  u16*   W1p   = (u16*)  alloc(65536*2);
  u16*   W2p   = (u16*)  alloc(65536*2);
  // gbuf (nbuck*CAP*4 ~ 19.2MB) aliases hA (51.2MB): dead before gemm0 writes hA
  u32*   gbuf  = (u32*)hA;

  int gn  = (n+255)/256;
  int gA  = (E+TILE-1)/TILE;
  int gp  = (n*64+255)/256;            // prop grid: one wave per row

  // graph build: 2-pass LDS-staged counting sort, fused metadata
  detect_k<<<1, 256, 0, stream>>>((const long long*)ei, flag, gcur, n, E, nbuck);
  binA_k  <<<gA, 256, 0, stream>>>(ei, flag, gcur, gbuf, E, n, nbuck);
  scanG_k <<<1, 256, 0, stream>>>(gcur, gstart, nbuck);
  csrB_k  <<<nbuck, 256, 0, stream>>>(gcur, gstart, gbuf, deg, dinv, rs, csr, n, nbuck);

  // weights
  pack2_k <<<512, 256, 0, stream>>>(W1, W2, W1p, W2p);

  // layer 0
  prop3_k <<<gn, 256, 0, stream>>>(x, csr, rs, deg, dinv, p0, n);
  gemm0_k <<<n, 256, 0, stream>>>(p0, W0, b0, dinv, hA, n);

  // layer 1
  prop256_k<<<gp, 256, 0, stream>>>(hA, hB, csr, rs, deg, dinv, n);
  gemm256_k<<<Mpad/64, 256, 0, stream>>>(hB, W1p, b1, dinv, hA, n);

  // layer 2
  prop256_k<<<gp, 256, 0, stream>>>(hA, hB, csr, rs, deg, dinv, n);
  gemm256_k<<<Mpad/64, 256, 0, stream>>>(hB, W2p, b2, dinv, hA, n);

  // layer 3 + skip
  gemm3_k <<<gn, 256, 0, stream>>>(hA, W3, qh, n);
  final_k <<<gn, 256, 0, stream>>>(qh, x, csr, rs, deg, dinv, b3, Wr, br, out, n);
}

// Round 10
// 875.864 us; speedup vs baseline: 1.4871x; 1.0035x over previous
//
#include <hip/hip_runtime.h>
#include <stdint.h>

typedef unsigned short u16;
typedef unsigned int u32;
typedef __attribute__((ext_vector_type(8))) short short8;
typedef __attribute__((ext_vector_type(4))) float f32x4;
typedef __attribute__((ext_vector_type(2))) unsigned int u32x2;

#define CAP 6144        // pairs per coarse bucket region (mean ~4096, +32 sigma margin)
#define TILE 4096       // edges per binA block

__device__ __forceinline__ float b2f_bits(u32 bits){ union{u32 u; float f;} v; v.u=bits; return v.f; }
__device__ __forceinline__ float bf_lo(u32 w){ return b2f_bits(w<<16); }
__device__ __forceinline__ float bf_hi(u32 w){ return b2f_bits(w & 0xffff0000u); }
__device__ __forceinline__ u16 f2bf(float f){
  union{float f; u32 u;} v; v.f=f;
  return (u16)((v.u + 0x7fffu + ((v.u>>16)&1u))>>16);   // round-to-nearest-even
}

// ---------------- graph build ----------------

// detect int64-vs-int32 edge layout AND zero the bucket cursors (fused)
__global__ void detect_k(const long long* __restrict__ ei, int* __restrict__ flag,
                         int* __restrict__ gcur, int n, int E, int nbuck){
  __shared__ int sh[256];
  int t = threadIdx.x;
  for(int i=t; i<nbuck; i+=256) gcur[i]=0;
  int lim = E/2 < 2048 ? E/2 : 2048;
  int bad = 0;
  for(int e=t; e<lim; e+=256){
    unsigned long long v = (unsigned long long)ei[e];
    if(v >= (unsigned long long)n) bad = 1;
  }
  sh[t]=bad; __syncthreads();
  for(int off=128; off>0; off>>=1){ if(t<off) sh[t] |= sh[t+off]; __syncthreads(); }
  if(t==0) *flag = sh[0];   // 1 => data is int32
}

__device__ __forceinline__ int edge_at(const void* eiv, int is32, long long idx){
  return is32 ? ((const int*)eiv)[idx] : (int)((const long long*)eiv)[idx];
}
__device__ __forceinline__ int clampi(int v, int lo, int hi){
  return v < lo ? lo : (v > hi ? hi : v);
}

// pass A: tile-level counting sort into coarse buckets (row>>7), pairs (r&127)<<17 | c
__global__ __launch_bounds__(256) void binA_k(const void* __restrict__ eiv, const int* __restrict__ flag,
                        int* __restrict__ gcur, u32* __restrict__ gbuf, int E, int n, int nbuck){
  __shared__ int hist[1024];
  __shared__ int base[1024];
  __shared__ int cur[1024];
  __shared__ int wsum[256];
  __shared__ u32 stage[TILE];
  int t = threadIdx.x;
  long long e0 = (long long)blockIdx.x * TILE;
  int cnt = (int)((long long)E - e0 < TILE ? (long long)E - e0 : TILE);
  int is32 = *flag;
  for(int i=t; i<nbuck; i+=256){ hist[i]=0; cur[i]=0; }
  __syncthreads();
  int eb[16]; u32 ep[16]; int ec=0;
  #pragma unroll
  for(int k=0;k<16;k++){
    int i = t + k*256;
    if(i<cnt){
      long long e = e0 + i;
      int r = clampi(edge_at(eiv,is32,e),0,n-1);
      int c = clampi(edge_at(eiv,is32,(long long)E+e),0,n-1);
      eb[ec] = r>>7;
      ep[ec] = ((u32)(r&127)<<17) | (u32)c;
      atomicAdd(&hist[eb[ec]],1);
      ec++;
    }
  }
  __syncthreads();
  int l[4]; int tot=0;
  #pragma unroll
  for(int j=0;j<4;j++){ int idx=t*4+j; l[j]=(idx<nbuck)?hist[idx]:0; tot+=l[j]; }
  wsum[t]=tot; __syncthreads();
  for(int off=1;off<256;off<<=1){
    int x = (t>=off)?wsum[t-off]:0;
    __syncthreads();
    wsum[t]+=x;
    __syncthreads();
  }
  int excl = wsum[t]-tot;
  #pragma unroll
  for(int j=0;j<4;j++){ int idx=t*4+j; if(idx<nbuck) base[idx]=excl; excl+=l[j]; }
  __syncthreads();
  for(int k=0;k<ec;k++){
    int b = eb[k];
    int slot = base[b] + atomicAdd(&cur[b],1);
    stage[slot] = ep[k];
  }
  __syncthreads();
  for(int b=t; b<nbuck; b+=256){
    int c = hist[b];
    if(c>0){
      int g = atomicAdd(&gcur[b], c);
      if(g > CAP) g = CAP;
      if(g + c > CAP) c = CAP - g;
      int src = base[b];
      u32* dst = gbuf + (size_t)b*CAP + g;
      for(int k=0;k<c;k++) dst[k] = stage[src+k];
    }
  }
}

// scan of per-bucket counts -> global bucket starts (one block)
__global__ __launch_bounds__(256) void scanG_k(const int* __restrict__ gcnt, int* __restrict__ gstart, int nbuck){
  __shared__ int sh[256];
  int t = threadIdx.x;
  int v[4]; int s=0;
  #pragma unroll
  for(int j=0;j<4;j++){
    int idx=t*4+j;
    int c = (idx<nbuck)?gcnt[idx]:0;
    if(c>CAP) c=CAP;
    v[j]=c; s+=c;
  }
  sh[t]=s; __syncthreads();
  for(int off=1;off<256;off<<=1){
    int x=(t>=off)?sh[t-off]:0;
    __syncthreads();
    sh[t]+=x;
    __syncthreads();
  }
  int excl = sh[t]-s;
  #pragma unroll
  for(int j=0;j<4;j++){ int idx=t*4+j; if(idx<nbuck) gstart[idx]=excl; excl+=v[j]; }
}

// pass B (fused): per-bucket degree + local scan + deg/dinv/rs outputs + CSR materialization
__global__ __launch_bounds__(256) void csrB_k(const int* __restrict__ gcnt, const int* __restrict__ gstart,
                        const u32* __restrict__ gbuf, int* __restrict__ deg, float* __restrict__ dinv,
                        int* __restrict__ rs, int* __restrict__ csr, int n, int nbuck){
  __shared__ int h[128], lst[128], lcur[128], sc[128];
  __shared__ int colstage[CAP];
  int b = blockIdx.x, t = threadIdx.x;
  if(t<128){ h[t]=0; lcur[t]=0; }
  __syncthreads();
  int c = gcnt[b]; if(c>CAP) c=CAP;
  const u32* p = gbuf + (size_t)b*CAP;
  for(int i=t;i<c;i+=256) atomicAdd(&h[p[i]>>17],1);
  __syncthreads();
  int dv=0;
  if(t<128){ dv=h[t]; sc[t]=dv; }
  __syncthreads();
  for(int off=1;off<128;off<<=1){
    int x=(t>=off&&t<128)?sc[t-off]:0;
    __syncthreads();
    if(t<128) sc[t]+=x;
    __syncthreads();
  }
  int g0 = gstart[b];
  if(t<128){
    lst[t]=sc[t]-dv;
    int row=b*128+t;
    if(row<n){
      deg[row]=dv;
      dinv[row]=rsqrtf((float)(dv+1));   // +1: self loop
      rs[row]=g0+lst[t];
    }
  }
  __syncthreads();
  for(int i=t;i<c;i+=256){
    u32 pr=p[i];
    int rl=pr>>17;
    int slot=lst[rl]+atomicAdd(&lcur[rl],1);
    if(slot<CAP) colstage[slot]=(int)(pr&0x1FFFFu);
  }
  __syncthreads();
  for(int i=t;i<c;i+=256) csr[g0+i]=colstage[i];
}

// ---------------- weights prep ----------------
// pack fp32 [256][256] W1,W2 into MFMA B-fragment order: [kk(8)][ct(16)][lane(64)][j(8)] bf16
__global__ void pack2_k(const float* __restrict__ W1, const float* __restrict__ W2,
                        u16* __restrict__ o1, u16* __restrict__ o2){
  int bid = blockIdx.x;
  const float* W = (bid<256)? W1 : W2;
  u16* out = (bid<256)? o1 : o2;
  int idx = (bid&255)*256 + threadIdx.x;   // 65536 per matrix
  int j  = idx & 7;
  int l  = (idx>>3) & 63;
  int ct = (idx>>9) & 15;
  int kk = idx>>13;
  int k  = kk*32 + (l>>4)*8 + j;
  int nn = ct*16 + (l&15);
  out[idx] = f2bf(W[k*256 + nn]);
}

// ---------------- fused layer 0: edge-parallel propagate + K=3 GEMM ----------------
// one block per row: gather row's neighbors edge-parallel, LDS-reduce 3 sums, then 256-col matmul
__global__ __launch_bounds__(256) void gemm0f_k(const float* __restrict__ x, const int* __restrict__ csr,
                        const int* __restrict__ rs, const int* __restrict__ deg,
                        const float* __restrict__ dinv, const float* __restrict__ W0,
                        const float* __restrict__ b0, u16* __restrict__ h1, int n){
  __shared__ float s0[256], s1[256], s2[256];
  __shared__ float pr[3];
  int i = blockIdx.x;
  int t = threadIdx.x;
  int s = rs[i], d = deg[i];
  float a0=0.f, a1=0.f, a2=0.f;
  for(int e=t; e<d; e+=256){
    int c = csr[s+e];
    float w = dinv[c];
    a0 += w*x[c*3+0]; a1 += w*x[c*3+1]; a2 += w*x[c*3+2];
  }
  s0[t]=a0; s1[t]=a1; s2[t]=a2; __syncthreads();
  for(int off=128; off>0; off>>=1){
    if(t<off){ s0[t]+=s0[t+off]; s1[t]+=s1[t+off]; s2[t]+=s2[t+off]; }
    __syncthreads();
  }
  if(t==0){
    float di = dinv[i];
    pr[0] = di*(s0[0] + di*x[i*3+0]);
    pr[1] = di*(s1[0] + di*x[i*3+1]);
    pr[2] = di*(s2[0] + di*x[i*3+2]);
  }
  __syncthreads();
  float v = pr[0]*W0[t] + pr[1]*W0[256+t] + pr[2]*W0[512+t] + b0[t];
  v = fmaxf(v, 0.f) * dinv[i];
  h1[(size_t)i*256 + t] = f2bf(v);
}

// ---------------- propagate (256-wide bf16, one wave/row, 16 gathers in flight) ----------------
__global__ __launch_bounds__(256) void prop256_k(const u16* __restrict__ hin, u16* __restrict__ pout,
                          const int* __restrict__ csr, const int* __restrict__ rs,
                          const int* __restrict__ deg, const float* __restrict__ dinv, int n){
  int row = (blockIdx.x*256 + threadIdx.x) >> 6;
  if(row>=n) return;
  row = __builtin_amdgcn_readfirstlane(row);
  int lane = threadIdx.x & 63;
  int co = lane*4;
  const u16* hb = hin + co;
  uint2 sv = *(const uint2*)(hb + (size_t)row*256);
  float a0=bf_lo(sv.x), a1=bf_hi(sv.x), a2=bf_lo(sv.y), a3=bf_hi(sv.y);
  int s = __builtin_amdgcn_readfirstlane(rs[row]);
  int d = __builtin_amdgcn_readfirstlane(deg[row]);
  for(int base=0; base<d; base+=16){
    int cc[16]; u32 mk[16];
    #pragma unroll
    for(int j=0;j<16;j++){
      int ok = (base+j) < d;                 // wave-uniform
      cc[j] = csr[ok ? (s+base+j) : s];
      mk[j] = ok ? 0xffffffffu : 0u;
    }
    uint2 v[16];
    #pragma unroll
    for(int j=0;j<16;j++) v[j] = *(const uint2*)(hb + (size_t)cc[j]*256);
    #pragma unroll
    for(int j=0;j<16;j++){
      u32 xw = v[j].x & mk[j], yw = v[j].y & mk[j];
      a0 += bf_lo(xw); a1 += bf_hi(xw); a2 += bf_lo(yw); a3 += bf_hi(yw);
    }
  }
  float sc = dinv[row];
  u32x2 o;
  o.x = (u32)f2bf(a0*sc) | ((u32)f2bf(a1*sc)<<16);
  o.y = (u32)f2bf(a2*sc) | ((u32)f2bf(a3*sc)<<16);
  __builtin_nontemporal_store(o, (u32x2*)(pout + (size_t)row*256 + co));
}

// ---------------- GEMM (layer 1): out = dinv*relu(A@W+b) ----------------
__global__ __launch_bounds__(256) void gemm256_k(const u16* __restrict__ A, const u16* __restrict__ Bp,
                          const float* __restrict__ bias, const float* __restrict__ dinv,
                          u16* __restrict__ Out, int M){
  int wave = threadIdx.x>>6, lane = threadIdx.x&63;
  int rowbase = blockIdx.x*64 + wave*16;
  f32x4 acc[16];
  #pragma unroll
  for(int t=0;t<16;t++){ acc[t][0]=0.f; acc[t][1]=0.f; acc[t][2]=0.f; acc[t][3]=0.f; }
  const u16* Ap = A + (size_t)(rowbase + (lane&15))*256 + ((lane>>4)*8);
  const u16* Bl = Bp + (size_t)lane*8;
  #pragma unroll
  for(int kk=0; kk<8; kk++){
    short8 af = __builtin_nontemporal_load((const short8*)(Ap + kk*32));   // streaming, read-once
    const u16* bb = Bl + (size_t)kk*8192;
    #pragma unroll
    for(int t=0;t<16;t++){
      short8 bf = *(const short8*)(bb + t*512);
      acc[t] = __builtin_amdgcn_mfma_f32_16x16x32_bf16(af, bf, acc[t], 0, 0, 0);
    }
  }
  int r0 = rowbase + (lane>>4)*4;
  float dv[4]; bool ok[4];
  #pragma unroll
  for(int r=0;r<4;r++){ ok[r] = (r0+r) < M; dv[r] = ok[r] ? dinv[r0+r] : 0.f; }
  #pragma unroll
  for(int t=0;t<16;t++){
    int col = t*16 + (lane&15);
    float bc = bias[col];
    #pragma unroll
    for(int r=0;r<4;r++){
      if(ok[r]){
        float v = fmaxf(acc[t][r] + bc, 0.f) * dv[r];
        Out[(size_t)(r0+r)*256 + col] = f2bf(v);
      }
    }
  }
}

// ---------------- GEMM (layer 2) fused with W3 projection: qh = (dinv*relu(A@W+b)) @ W3 ----------------
// skips materializing h3 entirely (saves 50MB write + 50MB read)
__global__ __launch_bounds__(256) void gemm256w3_k(const u16* __restrict__ A, const u16* __restrict__ Bp,
                          const float* __restrict__ bias, const float* __restrict__ dinv,
                          const float* __restrict__ W3, float* __restrict__ qh, int M){
  __shared__ float w3s[768];
  for(int i=threadIdx.x; i<768; i+=256) w3s[i] = W3[i];
  __syncthreads();
  int wave = threadIdx.x>>6, lane = threadIdx.x&63;
  int rowbase = blockIdx.x*64 + wave*16;
  f32x4 acc[16];
  #pragma unroll
  for(int t=0;t<16;t++){ acc[t][0]=0.f; acc[t][1]=0.f; acc[t][2]=0.f; acc[t][3]=0.f; }
  const u16* Ap = A + (size_t)(rowbase + (lane&15))*256 + ((lane>>4)*8);
  const u16* Bl = Bp + (size_t)lane*8;
  #pragma unroll
  for(int kk=0; kk<8; kk++){
    short8 af = __builtin_nontemporal_load((const short8*)(Ap + kk*32));
    const u16* bb = Bl + (size_t)kk*8192;
    #pragma unroll
    for(int t=0;t<16;t++){
      short8 bf = *(const short8*)(bb + t*512);
      acc[t] = __builtin_amdgcn_mfma_f32_16x16x32_bf16(af, bf, acc[t], 0, 0, 0);
    }
  }
  int r0 = rowbase + (lane>>4)*4;
  int cl = lane & 15;
  float dv[4];
  #pragma unroll
  for(int r=0;r<4;r++) dv[r] = (r0+r) < M ? dinv[r0+r] : 0.f;   // 0 for pad rows -> contributes 0
  float q0[4]={0,0,0,0}, q1[4]={0,0,0,0}, q2[4]={0,0,0,0};
  #pragma unroll
  for(int t=0;t<16;t++){
    int col = t*16 + cl;
    float bc = bias[col];
    float w30=w3s[col*3+0], w31=w3s[col*3+1], w32=w3s[col*3+2];
    #pragma unroll
    for(int r=0;r<4;r++){
      float v = fmaxf(acc[t][r] + bc, 0.f) * dv[r];   // h3hat (unrounded)
      q0[r] += v*w30; q1[r] += v*w31; q2[r] += v*w32;
    }
  }
  // reduce across the 16 lanes that share a row group (lane bits 0-3)
  #pragma unroll
  for(int off=1; off<16; off<<=1){
    #pragma unroll
    for(int r=0;r<4;r++){
      q0[r] += __shfl_xor(q0[r], off);
      q1[r] += __shfl_xor(q1[r], off);
      q2[r] += __shfl_xor(q2[r], off);
    }
  }
  if(cl==0){
    #pragma unroll
    for(int r=0;r<4;r++){
      int row = r0 + r;
      if(row < M){
        qh[row*3+0]=q0[r]; qh[row*3+1]=q1[r]; qh[row*3+2]=q2[r];
      }
    }
  }
}

// ---------------- final: wave-per-row edge-parallel 3-wide propagate + skip ----------------
__global__ __launch_bounds__(256) void final2_k(const float* __restrict__ qh, const float* __restrict__ x,
                        const int* __restrict__ csr, const int* __restrict__ rs,
                        const int* __restrict__ deg, const float* __restrict__ dinv,
                        const float* __restrict__ b3, const float* __restrict__ Wr,
                        const float* __restrict__ br, float* __restrict__ out, int n){
  int row = (blockIdx.x*256 + threadIdx.x) >> 6;
  if(row>=n) return;
  row = __builtin_amdgcn_readfirstlane(row);
  int lane = threadIdx.x & 63;
  int s = __builtin_amdgcn_readfirstlane(rs[row]);
  int d = __builtin_amdgcn_readfirstlane(deg[row]);
  float a0=0.f, a1=0.f, a2=0.f;
  for(int e=lane; e<d; e+=64){
    int c = csr[s+e];
    a0 += qh[c*3+0]; a1 += qh[c*3+1]; a2 += qh[c*3+2];
  }
  #pragma unroll
  for(int off=32; off>0; off>>=1){
    a0 += __shfl_xor(a0, off);
    a1 += __shfl_xor(a1, off);
    a2 += __shfl_xor(a2, off);
  }
  if(lane==0){
    float di = dinv[row];
    a0 = di*(a0 + qh[row*3+0]);
    a1 = di*(a1 + qh[row*3+1]);
    a2 = di*(a2 + qh[row*3+2]);
    float x0=x[row*3+0], x1=x[row*3+1], x2=x[row*3+2];
    out[row*3+0] = a0 + b3[0] + x0*Wr[0] + x1*Wr[3] + x2*Wr[6] + br[0];
    out[row*3+1] = a1 + b3[1] + x0*Wr[1] + x1*Wr[4] + x2*Wr[7] + br[1];
    out[row*3+2] = a2 + b3[2] + x0*Wr[2] + x1*Wr[5] + x2*Wr[8] + br[2];
  }
}

// ---------------- launch ----------------
extern "C" void kernel_launch(void* const* d_in, const int* in_sizes, int n_in,
                              void* d_out, int out_size, void* d_ws, size_t ws_size,
                              hipStream_t stream) {
  const float* x  = (const float*)d_in[0];
  const void*  ei = d_in[1];
  const float* W0 = (const float*)d_in[2];
  const float* b0 = (const float*)d_in[3];
  const float* W1 = (const float*)d_in[4];
  const float* b1 = (const float*)d_in[5];
  const float* W2 = (const float*)d_in[6];
  const float* b2 = (const float*)d_in[7];
  const float* W3 = (const float*)d_in[8];
  const float* b3 = (const float*)d_in[9];
  const float* Wr = (const float*)d_in[10];
  const float* br = (const float*)d_in[11];
  float* out = (float*)d_out;

  int n = in_sizes[0]/3;
  int E = in_sizes[1]/2;
  int nbuck = (n+127)>>7;              // 128 rows per bucket
  int Mpad = ((n+63)/64)*64;

  char* p = (char*)d_ws;
  auto alloc = [&](size_t bytes)->char*{ char* r=p; p += (bytes+255)&~(size_t)255; return r; };
  int*   gcur  = (int*)  alloc((size_t)nbuck*4);
  int*   gstart= (int*)  alloc((size_t)nbuck*4);
  int*   deg   = (int*)  alloc((size_t)n*4);
  float* dinv  = (float*)alloc((size_t)n*4);
  int*   rs    = (int*)  alloc((size_t)n*4);
  int*   flag  = (int*)  alloc(256);
  int*   csr   = (int*)  alloc((size_t)E*4);
  u16*   hA    = (u16*)  alloc((size_t)Mpad*512);
  u16*   hB    = (u16*)  alloc((size_t)Mpad*512);
  float* qh    = (float*)alloc((size_t)n*12);
  u16*   W1p   = (u16*)  alloc(65536*2);
  u16*   W2p   = (u16*)  alloc(65536*2);
  // gbuf (nbuck*CAP*4 ~ 19.2MB) aliases hA (51.2MB): dead before gemm0f writes hA
  u32*   gbuf  = (u32*)hA;

  int gA  = (E+TILE-1)/TILE;
  int gp  = (n*64+255)/256;            // one wave per row

  // graph build: 2-pass LDS-staged counting sort, fused metadata
  detect_k<<<1, 256, 0, stream>>>((const long long*)ei, flag, gcur, n, E, nbuck);
  binA_k  <<<gA, 256, 0, stream>>>(ei, flag, gcur, gbuf, E, n, nbuck);
  scanG_k <<<1, 256, 0, stream>>>(gcur, gstart, nbuck);
  csrB_k  <<<nbuck, 256, 0, stream>>>(gcur, gstart, gbuf, deg, dinv, rs, csr, n, nbuck);

  // weights
  pack2_k <<<512, 256, 0, stream>>>(W1, W2, W1p, W2p);

  // layer 0 (fused propagate + K=3 GEMM)
  gemm0f_k<<<n, 256, 0, stream>>>(x, csr, rs, deg, dinv, W0, b0, hA, n);

  // layer 1
  prop256_k<<<gp, 256, 0, stream>>>(hA, hB, csr, rs, deg, dinv, n);
  gemm256_k<<<Mpad/64, 256, 0, stream>>>(hB, W1p, b1, dinv, hA, n);

  // layer 2 + W3 projection (fused; skips h3 materialization)
  prop256_k<<<gp, 256, 0, stream>>>(hA, hB, csr, rs, deg, dinv, n);
  gemm256w3_k<<<Mpad/64, 256, 0, stream>>>(hB, W2p, b2, dinv, W3, qh, n);

  // final propagate + skip
  final2_k<<<gp, 256, 0, stream>>>(qh, x, csr, rs, deg, dinv, b3, Wr, br, out, n);
}